// Round 1
// baseline (15374.557 us; speedup 1.0000x reference)
//
#include <hip/hip_runtime.h>
#include <stdint.h>
#include <stdio.h>

#define NN 100000
#define NE 500000
#define HID 128
#define NH 4
#define HD 32
#define LL 2
#define BM 64
#define PA 132

typedef unsigned short u16;
typedef unsigned int u32;

__device__ __forceinline__ float b2f(u32 lo16) {
  union { u32 u; float f; } c; c.u = lo16; return c.f;
}
__device__ __forceinline__ u16 f2b(float f) {
  union { float f; u32 u; } c; c.f = f;
  u32 u = c.u;
  u32 r = (u + 0x7FFFu + ((u >> 16) & 1u)) >> 16;
  return (u16)r;
}
__device__ __forceinline__ float geluf(float x) {
  return 0.5f * x * (1.0f + erff(x * 0.70710678118654752f));
}

// Build combined weights: WkA = Wk[l,t] * a_rel[l,r=t] * p_rel*scale (per head), WvM = Wv[l,t] * m_rel[l,r=t]
__global__ void combine_w(const float* __restrict__ Wk, const float* __restrict__ bk,
                          const float* __restrict__ Wv, const float* __restrict__ bv,
                          const float* __restrict__ a_rel, const float* __restrict__ m_rel,
                          const float* __restrict__ p_rel,
                          float* __restrict__ WkA, float* __restrict__ bkA,
                          float* __restrict__ WvM, float* __restrict__ bvM, int l) {
  int t = blockIdx.x;       // source type == relation id
  int which = blockIdx.y;   // 0 => k-side, 1 => v-side
  const float* W  = (which == 0 ? Wk : Wv) + (size_t)(l * 2 + t) * HID * HID;
  const float* b  = (which == 0 ? bk : bv) + (size_t)(l * 2 + t) * HID;
  const float* Ar = (which == 0 ? a_rel : m_rel) + (size_t)(l * 2 + t) * NH * HD * HD;
  float* Wd = (which == 0 ? WkA : WvM) + (size_t)t * HID * HID;
  float* bd = (which == 0 ? bkA : bvM) + (size_t)t * HID;
  const float scale = 0.17677669529663687f;  // 1/sqrt(32)
  for (int idx = threadIdx.x; idx < HID * HID; idx += blockDim.x) {
    int i = idx >> 7, col = idx & 127;
    int h = col >> 5, e = col & 31;
    const float* ap = Ar + h * HD * HD + e;
    const float* wp = W + i * HID + h * HD;
    float s = 0.f;
#pragma unroll
    for (int d = 0; d < HD; ++d) s += wp[d] * ap[d * HD];
    if (which == 0) s *= p_rel[(l * 2 + t) * NH + h] * scale;
    Wd[idx] = s;
  }
  if (threadIdx.x < HID) {
    int col = threadIdx.x, h = col >> 5, e = col & 31;
    const float* ap = Ar + h * HD * HD + e;
    const float* bp = b + h * HD;
    float s = 0.f;
#pragma unroll
    for (int d = 0; d < HD; ++d) s += bp[d] * ap[d * HD];
    if (which == 0) s *= p_rel[(l * 2 + t) * NH + h] * scale;
    bd[col] = s;
  }
}

// C[M x 128] = epilogue( act_in(A[M x 128]) @ W[128 x 128] + b ), up to 3 weight sets sharing A.
template <int NMAT, bool INGELU, bool OUTRELU, bool SKIP, bool OBF16>
__global__ __launch_bounds__(256) void gemm128(
    const float* __restrict__ A, int M,
    const float* __restrict__ W0, const float* __restrict__ B0,
    const float* __restrict__ W1, const float* __restrict__ B1,
    const float* __restrict__ W2, const float* __restrict__ B2,
    void* __restrict__ O0, void* __restrict__ O1, void* __restrict__ O2,
    const float* __restrict__ hprev, const float* __restrict__ skipP, int resflag) {
  __shared__ float sA[BM * PA];
  const int tid = threadIdx.x;
  const int tx = tid & 15, ty = tid >> 4;
  const int r0 = blockIdx.x * BM;
  {
    int kv = tid & 31;   // float4 index within row
    int rb = tid >> 5;   // 0..7
#pragma unroll
    for (int pss = 0; pss < 8; ++pss) {
      int r = pss * 8 + rb;
      int gr = r0 + r;
      float4 v = make_float4(0.f, 0.f, 0.f, 0.f);
      if (gr < M) v = *(const float4*)(A + (size_t)gr * HID + kv * 4);
      if (INGELU) { v.x = geluf(v.x); v.y = geluf(v.y); v.z = geluf(v.z); v.w = geluf(v.w); }
      float* d = sA + r * PA + kv * 4;
      d[0] = v.x; d[1] = v.y; d[2] = v.z; d[3] = v.w;
    }
  }
  __syncthreads();

  const float* Ws[3] = {W0, W1, W2};
  const float* Bs[3] = {B0, B1, B2};
  void* Os[3] = {O0, O1, O2};

  float beta = 0.f;
  if (SKIP) beta = 1.f / (1.f + expf(-skipP[0]));

#pragma unroll
  for (int mat = 0; mat < NMAT; ++mat) {
    const float* __restrict__ W = Ws[mat];
    float acc[4][8];
#pragma unroll
    for (int m = 0; m < 4; ++m)
#pragma unroll
      for (int j = 0; j < 8; ++j) acc[m][j] = 0.f;
    const float* Wp = W + tx * 8;
#pragma unroll 4
    for (int k = 0; k < HID; ++k) {
      float4 w0 = *(const float4*)(Wp + (size_t)k * HID);
      float4 w1 = *(const float4*)(Wp + (size_t)k * HID + 4);
#pragma unroll
      for (int m = 0; m < 4; ++m) {
        float a = sA[(ty + 16 * m) * PA + k];
        acc[m][0] += a * w0.x; acc[m][1] += a * w0.y;
        acc[m][2] += a * w0.z; acc[m][3] += a * w0.w;
        acc[m][4] += a * w1.x; acc[m][5] += a * w1.y;
        acc[m][6] += a * w1.z; acc[m][7] += a * w1.w;
      }
    }
    const float* Bp = Bs[mat] + tx * 8;
    float bias[8];
#pragma unroll
    for (int j = 0; j < 8; ++j) bias[j] = Bp[j];
#pragma unroll
    for (int m = 0; m < 4; ++m) {
      int r = r0 + ty + 16 * m;
      if (r >= M) continue;
      float o[8];
#pragma unroll
      for (int j = 0; j < 8; ++j) {
        float v = acc[m][j] + bias[j];
        if (OUTRELU) v = fmaxf(v, 0.f);
        o[j] = v;
      }
      if (SKIP) {
        const float* hp = hprev + (size_t)r * HID + tx * 8;
#pragma unroll
        for (int j = 0; j < 8; ++j) {
          float h = hp[j];
          float v = beta * o[j] + (1.f - beta) * h;
          if (resflag) v += h;
          o[j] = v;
        }
      }
      if (OBF16) {
        u16* Ob = (u16*)Os[mat] + (size_t)r * HID + tx * 8;
        union { u16 s[8]; uint4 v; } pk;
#pragma unroll
        for (int j = 0; j < 8; ++j) pk.s[j] = f2b(o[j]);
        *(uint4*)Ob = pk.v;
      } else {
        float* Of = (float*)Os[mat] + (size_t)r * HID + tx * 8;
        *(float4*)Of = make_float4(o[0], o[1], o[2], o[3]);
        *(float4*)(Of + 4) = make_float4(o[4], o[5], o[6], o[7]);
      }
    }
  }
}

// Pass A: e = exp(q[dst] . kr[src]) per (edge, head); z[dst,h] += e
__global__ __launch_bounds__(256) void edge_logits(
    const int* __restrict__ edges, const u16* __restrict__ qT,
    const u16* __restrict__ kT, float* __restrict__ est, float* __restrict__ z) {
  int i = blockIdx.x * blockDim.x + threadIdx.x;
  if (i >= NE * NH) return;
  int e = i >> 2, h = i & 3;
  int src = edges[e], dst = edges[NE + e];
  const uint4* qp = (const uint4*)(qT + (size_t)dst * HID + h * HD);
  const uint4* kp = (const uint4*)(kT + (size_t)src * HID + h * HD);
  float s = 0.f;
#pragma unroll
  for (int j = 0; j < 4; ++j) {
    uint4 qa = qp[j], ka = kp[j];
    u32 qa_[4] = {qa.x, qa.y, qa.z, qa.w};
    u32 ka_[4] = {ka.x, ka.y, ka.z, ka.w};
#pragma unroll
    for (int q = 0; q < 4; ++q) {
      float ql = b2f(qa_[q] << 16), qh = b2f(qa_[q] & 0xFFFF0000u);
      float kl = b2f(ka_[q] << 16), kh = b2f(ka_[q] & 0xFFFF0000u);
      s += ql * kl + qh * kh;
    }
  }
  s = fminf(s, 60.f);
  float ev = expf(s);
  est[i] = ev;
  atomicAdd(&z[(size_t)dst * NH + h], ev);
}

// Pass B: agg[dst] += (e/z) * vr[src]
__global__ __launch_bounds__(256) void edge_msg(
    const int* __restrict__ edges, const u16* __restrict__ vT,
    const float* __restrict__ est, const float* __restrict__ z,
    float* __restrict__ agg) {
  int i = blockIdx.x * blockDim.x + threadIdx.x;
  if (i >= NE * NH) return;
  int e = i >> 2, h = i & 3;
  int src = edges[e], dst = edges[NE + e];
  float w = est[i] / (z[(size_t)dst * NH + h] + 1e-16f);
  const uint4* vp = (const uint4*)(vT + (size_t)src * HID + h * HD);
  float* ap = agg + (size_t)dst * HID + h * HD;
#pragma unroll
  for (int j = 0; j < 4; ++j) {
    uint4 va = vp[j];
    u32 va_[4] = {va.x, va.y, va.z, va.w};
#pragma unroll
    for (int q = 0; q < 4; ++q) {
      atomicAdd(ap + j * 8 + q * 2, w * b2f(va_[q] << 16));
      atomicAdd(ap + j * 8 + q * 2 + 1, w * b2f(va_[q] & 0xFFFF0000u));
    }
  }
}

extern "C" void kernel_launch(void* const* d_in, const int* in_sizes, int n_in,
                              void* d_out, int out_size, void* d_ws, size_t ws_size,
                              hipStream_t stream) {
  const float* x_user = (const float*)d_in[0];
  const float* x_item = (const float*)d_in[1];
  const float* W_in = (const float*)d_in[2];
  const float* b_in = (const float*)d_in[3];
  const float* Wk = (const float*)d_in[4];
  const float* bk = (const float*)d_in[5];
  const float* Wq = (const float*)d_in[6];
  const float* bq = (const float*)d_in[7];
  const float* Wv = (const float*)d_in[8];
  const float* bv = (const float*)d_in[9];
  const float* a_rel = (const float*)d_in[10];
  const float* m_rel = (const float*)d_in[11];
  const float* p_rel = (const float*)d_in[12];
  const float* Wo = (const float*)d_in[13];
  const float* bo = (const float*)d_in[14];
  const float* skipP = (const float*)d_in[15];
  const int* edge_ui = (const int*)d_in[16];
  const int* edge_iu = (const int*)d_in[17];
  float* out = (float*)d_out;

  char* p = (char*)d_ws;
  auto take = [&](size_t bytes) {
    void* r = (void*)p;
    p += (bytes + 255) & ~(size_t)255;
    return r;
  };
  size_t nodeF = (size_t)NN * HID * sizeof(float);
  size_t nodeB = (size_t)NN * HID * sizeof(u16);
  float* hA[2] = {(float*)take(nodeF), (float*)take(nodeF)};
  float* hB[2] = {(float*)take(nodeF), (float*)take(nodeF)};
  u16* qb[2] = {(u16*)take(nodeB), (u16*)take(nodeB)};
  u16* kb[2] = {(u16*)take(nodeB), (u16*)take(nodeB)};
  u16* vb[2] = {(u16*)take(nodeB), (u16*)take(nodeB)};
  float* zb[2] = {(float*)take((size_t)NN * NH * 4), (float*)take((size_t)NN * NH * 4)};
  float* est[2] = {(float*)take((size_t)NE * NH * 4), (float*)take((size_t)NE * NH * 4)};
  float* WkA = (float*)take((size_t)2 * HID * HID * 4);
  float* bkA = (float*)take((size_t)2 * HID * 4);
  float* WvM = (float*)take((size_t)2 * HID * HID * 4);
  float* bvM = (float*)take((size_t)2 * HID * 4);
  size_t used = (size_t)(p - (char*)d_ws);
  if (used > ws_size) {
    fprintf(stderr, "HGT kernel: workspace too small: need %zu, have %zu\n", used, ws_size);
    return;
  }

  const int GB = (NN + BM - 1) / BM;
  dim3 blk(256);

  // input linear + relu
  gemm128<1, false, true, false, false><<<GB, blk, 0, stream>>>(
      x_user, NN, W_in, b_in, nullptr, nullptr, nullptr, nullptr,
      hA[0], nullptr, nullptr, nullptr, nullptr, 0);
  gemm128<1, false, true, false, false><<<GB, blk, 0, stream>>>(
      x_item, NN, W_in + HID * HID, b_in + HID, nullptr, nullptr, nullptr, nullptr,
      hA[1], nullptr, nullptr, nullptr, nullptr, 0);

  float* cur[2] = {hA[0], hA[1]};
  float* nxt[2] = {hB[0], hB[1]};
  const int* eidx[2] = {edge_ui, edge_iu};
  const int EG = (NE * NH + 255) / 256;

  for (int l = 0; l < LL; ++l) {
    combine_w<<<dim3(2, 2), blk, 0, stream>>>(Wk, bk, Wv, bv, a_rel, m_rel, p_rel,
                                              WkA, bkA, WvM, bvM, l);
    hipMemsetAsync(zb[0], 0, (size_t)NN * NH * 4, stream);
    hipMemsetAsync(zb[1], 0, (size_t)NN * NH * 4, stream);
    hipMemsetAsync(nxt[0], 0, nodeF, stream);
    hipMemsetAsync(nxt[1], 0, nodeF, stream);

    for (int t = 0; t < 2; ++t) {
      gemm128<3, false, false, false, true><<<GB, blk, 0, stream>>>(
          cur[t], NN,
          Wq + (size_t)(l * 2 + t) * HID * HID, bq + (size_t)(l * 2 + t) * HID,
          WkA + (size_t)t * HID * HID, bkA + (size_t)t * HID,
          WvM + (size_t)t * HID * HID, bvM + (size_t)t * HID,
          qb[t], kb[t], vb[t], nullptr, nullptr, 0);
    }
    for (int r = 0; r < 2; ++r) {
      int st = r, dt = 1 - r;
      edge_logits<<<EG, blk, 0, stream>>>(eidx[r], qb[dt], kb[st], est[r], zb[dt]);
    }
    for (int r = 0; r < 2; ++r) {
      int st = r, dt = 1 - r;
      edge_msg<<<EG, blk, 0, stream>>>(eidx[r], vb[st], est[r], zb[dt], nxt[dt]);
    }
    for (int t = 0; t < 2; ++t) {
      float* outp = (l == LL - 1) ? (out + (size_t)t * NN * HID) : nxt[t];
      gemm128<1, true, false, true, false><<<GB, blk, 0, stream>>>(
          nxt[t], NN, Wo + (size_t)(l * 2 + t) * HID * HID, bo + (size_t)(l * 2 + t) * HID,
          nullptr, nullptr, nullptr, nullptr,
          outp, nullptr, nullptr, cur[t], skipP + (l * 2 + t), l > 0 ? 1 : 0);
    }
    if (l == 0) {
      float* t0 = cur[0]; float* t1 = cur[1];
      cur[0] = nxt[0]; cur[1] = nxt[1];
      nxt[0] = t0; nxt[1] = t1;
    }
  }
}

// Round 2
// 2125.826 us; speedup vs baseline: 7.2323x; 7.2323x over previous
//
#include <hip/hip_runtime.h>
#include <stdint.h>
#include <stdio.h>

#define NN 100000
#define NE 500000
#define HID 128
#define NH 4
#define HD 32
#define LL 2
#define BM 64
#define PA 132

typedef unsigned short u16;
typedef unsigned int u32;

__device__ __forceinline__ float b2f(u32 lo16) {
  union { u32 u; float f; } c; c.u = lo16; return c.f;
}
__device__ __forceinline__ u16 f2b(float f) {
  union { float f; u32 u; } c; c.f = f;
  u32 u = c.u;
  u32 r = (u + 0x7FFFu + ((u >> 16) & 1u)) >> 16;
  return (u16)r;
}
__device__ __forceinline__ float geluf(float x) {
  return 0.5f * x * (1.0f + erff(x * 0.70710678118654752f));
}
__device__ __forceinline__ void up8(uint4 a, float* f) {
  f[0] = b2f(a.x << 16); f[1] = b2f(a.x & 0xFFFF0000u);
  f[2] = b2f(a.y << 16); f[3] = b2f(a.y & 0xFFFF0000u);
  f[4] = b2f(a.z << 16); f[5] = b2f(a.z & 0xFFFF0000u);
  f[6] = b2f(a.w << 16); f[7] = b2f(a.w & 0xFFFF0000u);
}

// ---------------- CSR build (per relation, layer-independent) ----------------
__global__ __launch_bounds__(256) void csr_count(const int* __restrict__ edges,
                                                 int* __restrict__ deg) {
  int e = blockIdx.x * blockDim.x + threadIdx.x;
  if (e < NE) atomicAdd(&deg[edges[NE + e]], 1);
}

__global__ __launch_bounds__(1024) void scan_deg(const int* __restrict__ deg,
                                                 int* __restrict__ rowptr,
                                                 int* __restrict__ cursor) {
  __shared__ int ls[1024];
  int tid = threadIdx.x;
  const int CH = (NN + 1023) / 1024;  // 98
  int base = tid * CH;
  int s = 0;
  for (int i = 0; i < CH; ++i) {
    int idx = base + i;
    if (idx < NN) s += deg[idx];
  }
  ls[tid] = s;
  __syncthreads();
  for (int off = 1; off < 1024; off <<= 1) {
    int v = (tid >= off) ? ls[tid - off] : 0;
    __syncthreads();
    ls[tid] += v;
    __syncthreads();
  }
  int run = ls[tid] - s;  // exclusive prefix
  for (int i = 0; i < CH; ++i) {
    int idx = base + i;
    if (idx < NN) {
      rowptr[idx] = run;
      cursor[idx] = run;
      run += deg[idx];
    }
  }
  if (tid == 0) rowptr[NN] = NE;
}

__global__ __launch_bounds__(256) void csr_fill(const int* __restrict__ edges,
                                                int* __restrict__ cursor,
                                                int* __restrict__ srcs) {
  int e = blockIdx.x * blockDim.x + threadIdx.x;
  if (e < NE) {
    int pos = atomicAdd(&cursor[edges[NE + e]], 1);
    srcs[pos] = edges[e];
  }
}

// Fused per-(dst,head) attention gather: logits -> softmax -> weighted V sum.
__global__ __launch_bounds__(256) void agg_csr(
    const int* __restrict__ rowptr, const int* __restrict__ srcs,
    const u16* __restrict__ qT, const u16* __restrict__ kT,
    const u16* __restrict__ vT, float* __restrict__ agg) {
  int i = blockIdx.x * blockDim.x + threadIdx.x;
  if (i >= NN * NH) return;
  int dst = i >> 2, h = i & 3;
  float qv[HD];
  {
    const uint4* qp = (const uint4*)(qT + (size_t)dst * HID + h * HD);
#pragma unroll
    for (int j = 0; j < 4; ++j) up8(qp[j], qv + j * 8);
  }
  float acc[HD];
#pragma unroll
  for (int j = 0; j < HD; ++j) acc[j] = 0.f;
  float z = 0.f;
  int b = rowptr[dst], e2 = rowptr[dst + 1];
  for (int idx = b; idx < e2; ++idx) {
    int src = srcs[idx];
    const uint4* kp = (const uint4*)(kT + (size_t)src * HID + h * HD);
    const uint4* vp = (const uint4*)(vT + (size_t)src * HID + h * HD);
    uint4 ka[4], va[4];
#pragma unroll
    for (int j = 0; j < 4; ++j) ka[j] = kp[j];
#pragma unroll
    for (int j = 0; j < 4; ++j) va[j] = vp[j];
    float tf[8];
    float s = 0.f;
#pragma unroll
    for (int j = 0; j < 4; ++j) {
      up8(ka[j], tf);
#pragma unroll
      for (int q = 0; q < 8; ++q) s += qv[j * 8 + q] * tf[q];
    }
    s = fminf(s, 60.f);
    float ev = __expf(s);
    z += ev;
#pragma unroll
    for (int j = 0; j < 4; ++j) {
      up8(va[j], tf);
#pragma unroll
      for (int q = 0; q < 8; ++q) acc[j * 8 + q] += ev * tf[q];
    }
  }
  float inv = 1.f / (z + 1e-16f);
  float* ap = agg + (size_t)dst * HID + h * HD;
#pragma unroll
  for (int j = 0; j < 8; ++j) {
    *(float4*)(ap + j * 4) = make_float4(acc[j * 4] * inv, acc[j * 4 + 1] * inv,
                                         acc[j * 4 + 2] * inv, acc[j * 4 + 3] * inv);
  }
}

// Build combined weights: WkA = Wk[l,t] * a_rel[l,r=t] * p_rel*scale, WvM = Wv[l,t] * m_rel[l,r=t]
__global__ void combine_w(const float* __restrict__ Wk, const float* __restrict__ bk,
                          const float* __restrict__ Wv, const float* __restrict__ bv,
                          const float* __restrict__ a_rel, const float* __restrict__ m_rel,
                          const float* __restrict__ p_rel,
                          float* __restrict__ WkA, float* __restrict__ bkA,
                          float* __restrict__ WvM, float* __restrict__ bvM, int l) {
  int t = blockIdx.x;       // source type == relation id
  int which = blockIdx.y;   // 0 => k-side, 1 => v-side
  const float* W  = (which == 0 ? Wk : Wv) + (size_t)(l * 2 + t) * HID * HID;
  const float* b  = (which == 0 ? bk : bv) + (size_t)(l * 2 + t) * HID;
  const float* Ar = (which == 0 ? a_rel : m_rel) + (size_t)(l * 2 + t) * NH * HD * HD;
  float* Wd = (which == 0 ? WkA : WvM) + (size_t)t * HID * HID;
  float* bd = (which == 0 ? bkA : bvM) + (size_t)t * HID;
  const float scale = 0.17677669529663687f;  // 1/sqrt(32)
  for (int idx = threadIdx.x; idx < HID * HID; idx += blockDim.x) {
    int i = idx >> 7, col = idx & 127;
    int h = col >> 5, e = col & 31;
    const float* ap = Ar + h * HD * HD + e;
    const float* wp = W + i * HID + h * HD;
    float s = 0.f;
#pragma unroll
    for (int d = 0; d < HD; ++d) s += wp[d] * ap[d * HD];
    if (which == 0) s *= p_rel[(l * 2 + t) * NH + h] * scale;
    Wd[idx] = s;
  }
  if (threadIdx.x < HID) {
    int col = threadIdx.x, h = col >> 5, e = col & 31;
    const float* ap = Ar + h * HD * HD + e;
    const float* bp = b + h * HD;
    float s = 0.f;
#pragma unroll
    for (int d = 0; d < HD; ++d) s += bp[d] * ap[d * HD];
    if (which == 0) s *= p_rel[(l * 2 + t) * NH + h] * scale;
    bd[col] = s;
  }
}

// C[M x 128] = epilogue( act_in(A[M x 128]) @ W[128 x 128] + b ), up to 3 weight sets sharing A.
template <int NMAT, bool INGELU, bool OUTRELU, bool SKIP, bool OBF16>
__global__ __launch_bounds__(256) void gemm128(
    const float* __restrict__ A, int M,
    const float* __restrict__ W0, const float* __restrict__ B0,
    const float* __restrict__ W1, const float* __restrict__ B1,
    const float* __restrict__ W2, const float* __restrict__ B2,
    void* __restrict__ O0, void* __restrict__ O1, void* __restrict__ O2,
    const float* __restrict__ hprev, const float* __restrict__ skipP, int resflag) {
  __shared__ float sA[BM * PA];
  const int tid = threadIdx.x;
  const int tx = tid & 15, ty = tid >> 4;
  const int r0 = blockIdx.x * BM;
  {
    int kv = tid & 31;   // float4 index within row
    int rb = tid >> 5;   // 0..7
#pragma unroll
    for (int pss = 0; pss < 8; ++pss) {
      int r = pss * 8 + rb;
      int gr = r0 + r;
      float4 v = make_float4(0.f, 0.f, 0.f, 0.f);
      if (gr < M) v = *(const float4*)(A + (size_t)gr * HID + kv * 4);
      if (INGELU) { v.x = geluf(v.x); v.y = geluf(v.y); v.z = geluf(v.z); v.w = geluf(v.w); }
      float* d = sA + r * PA + kv * 4;
      d[0] = v.x; d[1] = v.y; d[2] = v.z; d[3] = v.w;
    }
  }
  __syncthreads();

  const float* Ws[3] = {W0, W1, W2};
  const float* Bs[3] = {B0, B1, B2};
  void* Os[3] = {O0, O1, O2};

  float beta = 0.f;
  if (SKIP) beta = 1.f / (1.f + expf(-skipP[0]));

#pragma unroll
  for (int mat = 0; mat < NMAT; ++mat) {
    const float* __restrict__ W = Ws[mat];
    float acc[4][8];
#pragma unroll
    for (int m = 0; m < 4; ++m)
#pragma unroll
      for (int j = 0; j < 8; ++j) acc[m][j] = 0.f;
    const float* Wp = W + tx * 8;
#pragma unroll 4
    for (int k = 0; k < HID; ++k) {
      float4 w0 = *(const float4*)(Wp + (size_t)k * HID);
      float4 w1 = *(const float4*)(Wp + (size_t)k * HID + 4);
#pragma unroll
      for (int m = 0; m < 4; ++m) {
        float a = sA[(ty + 16 * m) * PA + k];
        acc[m][0] += a * w0.x; acc[m][1] += a * w0.y;
        acc[m][2] += a * w0.z; acc[m][3] += a * w0.w;
        acc[m][4] += a * w1.x; acc[m][5] += a * w1.y;
        acc[m][6] += a * w1.z; acc[m][7] += a * w1.w;
      }
    }
    const float* Bp = Bs[mat] + tx * 8;
    float bias[8];
#pragma unroll
    for (int j = 0; j < 8; ++j) bias[j] = Bp[j];
#pragma unroll
    for (int m = 0; m < 4; ++m) {
      int r = r0 + ty + 16 * m;
      if (r >= M) continue;
      float o[8];
#pragma unroll
      for (int j = 0; j < 8; ++j) {
        float v = acc[m][j] + bias[j];
        if (OUTRELU) v = fmaxf(v, 0.f);
        o[j] = v;
      }
      if (SKIP) {
        const float* hp = hprev + (size_t)r * HID + tx * 8;
#pragma unroll
        for (int j = 0; j < 8; ++j) {
          float h = hp[j];
          float v = beta * o[j] + (1.f - beta) * h;
          if (resflag) v += h;
          o[j] = v;
        }
      }
      if (OBF16) {
        u16* Ob = (u16*)Os[mat] + (size_t)r * HID + tx * 8;
        union { u16 s[8]; uint4 v; } pk;
#pragma unroll
        for (int j = 0; j < 8; ++j) pk.s[j] = f2b(o[j]);
        *(uint4*)Ob = pk.v;
      } else {
        float* Of = (float*)Os[mat] + (size_t)r * HID + tx * 8;
        *(float4*)Of = make_float4(o[0], o[1], o[2], o[3]);
        *(float4*)(Of + 4) = make_float4(o[4], o[5], o[6], o[7]);
      }
    }
  }
}

extern "C" void kernel_launch(void* const* d_in, const int* in_sizes, int n_in,
                              void* d_out, int out_size, void* d_ws, size_t ws_size,
                              hipStream_t stream) {
  const float* x_user = (const float*)d_in[0];
  const float* x_item = (const float*)d_in[1];
  const float* W_in = (const float*)d_in[2];
  const float* b_in = (const float*)d_in[3];
  const float* Wk = (const float*)d_in[4];
  const float* bk = (const float*)d_in[5];
  const float* Wq = (const float*)d_in[6];
  const float* bq = (const float*)d_in[7];
  const float* Wv = (const float*)d_in[8];
  const float* bv = (const float*)d_in[9];
  const float* a_rel = (const float*)d_in[10];
  const float* m_rel = (const float*)d_in[11];
  const float* p_rel = (const float*)d_in[12];
  const float* Wo = (const float*)d_in[13];
  const float* bo = (const float*)d_in[14];
  const float* skipP = (const float*)d_in[15];
  const int* edge_ui = (const int*)d_in[16];
  const int* edge_iu = (const int*)d_in[17];
  float* out = (float*)d_out;

  char* p = (char*)d_ws;
  auto take = [&](size_t bytes) {
    void* r = (void*)p;
    p += (bytes + 255) & ~(size_t)255;
    return r;
  };
  size_t nodeF = (size_t)NN * HID * sizeof(float);
  size_t nodeB = (size_t)NN * HID * sizeof(u16);
  float* hA[2] = {(float*)take(nodeF), (float*)take(nodeF)};
  float* hB[2] = {(float*)take(nodeF), (float*)take(nodeF)};
  u16* qb[2] = {(u16*)take(nodeB), (u16*)take(nodeB)};
  u16* kb[2] = {(u16*)take(nodeB), (u16*)take(nodeB)};
  u16* vb[2] = {(u16*)take(nodeB), (u16*)take(nodeB)};
  int* deg    = (int*)take((size_t)NN * 4);
  int* cursor = (int*)take((size_t)NN * 4);
  int* rowptr[2] = {(int*)take((size_t)(NN + 1) * 4), (int*)take((size_t)(NN + 1) * 4)};
  int* srcs[2]   = {(int*)take((size_t)NE * 4), (int*)take((size_t)NE * 4)};
  float* WkA = (float*)take((size_t)2 * HID * HID * 4);
  float* bkA = (float*)take((size_t)2 * HID * 4);
  float* WvM = (float*)take((size_t)2 * HID * HID * 4);
  float* bvM = (float*)take((size_t)2 * HID * 4);
  size_t used = (size_t)(p - (char*)d_ws);
  if (used > ws_size) {
    fprintf(stderr, "HGT kernel: workspace too small: need %zu, have %zu\n", used, ws_size);
    return;
  }

  const int GB = (NN + BM - 1) / BM;
  const int EB = (NE + 255) / 256;
  dim3 blk(256);
  const int* eidx[2] = {edge_ui, edge_iu};

  // ---- CSR build (once; shared by both layers) ----
  for (int r = 0; r < 2; ++r) {
    hipMemsetAsync(deg, 0, (size_t)NN * 4, stream);
    csr_count<<<EB, blk, 0, stream>>>(eidx[r], deg);
    scan_deg<<<1, 1024, 0, stream>>>(deg, rowptr[r], cursor);
    csr_fill<<<EB, blk, 0, stream>>>(eidx[r], cursor, srcs[r]);
  }

  // ---- input linear + relu ----
  gemm128<1, false, true, false, false><<<GB, blk, 0, stream>>>(
      x_user, NN, W_in, b_in, nullptr, nullptr, nullptr, nullptr,
      hA[0], nullptr, nullptr, nullptr, nullptr, 0);
  gemm128<1, false, true, false, false><<<GB, blk, 0, stream>>>(
      x_item, NN, W_in + HID * HID, b_in + HID, nullptr, nullptr, nullptr, nullptr,
      hA[1], nullptr, nullptr, nullptr, nullptr, 0);

  float* cur[2] = {hA[0], hA[1]};
  float* nxt[2] = {hB[0], hB[1]};
  const int AGB = (NN * NH + 255) / 256;

  for (int l = 0; l < LL; ++l) {
    combine_w<<<dim3(2, 2), blk, 0, stream>>>(Wk, bk, Wv, bv, a_rel, m_rel, p_rel,
                                              WkA, bkA, WvM, bvM, l);
    for (int t = 0; t < 2; ++t) {
      gemm128<3, false, false, false, true><<<GB, blk, 0, stream>>>(
          cur[t], NN,
          Wq + (size_t)(l * 2 + t) * HID * HID, bq + (size_t)(l * 2 + t) * HID,
          WkA + (size_t)t * HID * HID, bkA + (size_t)t * HID,
          WvM + (size_t)t * HID * HID, bvM + (size_t)t * HID,
          qb[t], kb[t], vb[t], nullptr, nullptr, 0);
    }
    for (int r = 0; r < 2; ++r) {
      int st = r, dt = 1 - r;
      agg_csr<<<AGB, blk, 0, stream>>>(rowptr[r], srcs[r], qb[dt], kb[st], vb[st], nxt[dt]);
    }
    for (int t = 0; t < 2; ++t) {
      float* outp = (l == LL - 1) ? (out + (size_t)t * NN * HID) : nxt[t];
      gemm128<1, true, false, true, false><<<GB, blk, 0, stream>>>(
          nxt[t], NN, Wo + (size_t)(l * 2 + t) * HID * HID, bo + (size_t)(l * 2 + t) * HID,
          nullptr, nullptr, nullptr, nullptr,
          outp, nullptr, nullptr, cur[t], skipP + (l * 2 + t), l > 0 ? 1 : 0);
    }
    if (l == 0) {
      float* t0 = cur[0]; float* t1 = cur[1];
      cur[0] = nxt[0]; cur[1] = nxt[1];
      nxt[0] = t0; nxt[1] = t1;
    }
  }
}

// Round 3
// 1616.475 us; speedup vs baseline: 9.5112x; 1.3151x over previous
//
#include <hip/hip_runtime.h>
#include <stdint.h>
#include <stdio.h>

#define NN 100000
#define NE 500000
#define HID 128
#define NH 4
#define HD 32
#define LL 2
#define BM 64
#define PA 132
#define SCANB 1024
#define NB ((NN + SCANB - 1) / SCANB)

typedef unsigned short u16;
typedef unsigned int u32;

__device__ __forceinline__ float b2f(u32 lo16) {
  union { u32 u; float f; } c; c.u = lo16; return c.f;
}
__device__ __forceinline__ u16 f2b(float f) {
  union { float f; u32 u; } c; c.f = f;
  u32 u = c.u;
  u32 r = (u + 0x7FFFu + ((u >> 16) & 1u)) >> 16;
  return (u16)r;
}
__device__ __forceinline__ float geluf(float x) {
  return 0.5f * x * (1.0f + erff(x * 0.70710678118654752f));
}
__device__ __forceinline__ void up8(uint4 a, float* f) {
  f[0] = b2f(a.x << 16); f[1] = b2f(a.x & 0xFFFF0000u);
  f[2] = b2f(a.y << 16); f[3] = b2f(a.y & 0xFFFF0000u);
  f[4] = b2f(a.z << 16); f[5] = b2f(a.z & 0xFFFF0000u);
  f[6] = b2f(a.w << 16); f[7] = b2f(a.w & 0xFFFF0000u);
}

// ---------------- CSR build (per relation, layer-independent) ----------------
__global__ __launch_bounds__(256) void csr_count(const int* __restrict__ edges,
                                                 int* __restrict__ deg) {
  int e = blockIdx.x * blockDim.x + threadIdx.x;
  if (e < NE) atomicAdd(&deg[edges[NE + e]], 1);
}

// 3-kernel device-wide exclusive scan of deg[NN] -> rowptr/cursor
__global__ __launch_bounds__(SCANB) void scan1(const int* __restrict__ deg,
                                               int* __restrict__ rowptr,
                                               int* __restrict__ bsum) {
  __shared__ int ls[SCANB];
  int t = threadIdx.x;
  int g = blockIdx.x * SCANB + t;
  int v = (g < NN) ? deg[g] : 0;
  ls[t] = v;
  __syncthreads();
#pragma unroll
  for (int off = 1; off < SCANB; off <<= 1) {
    int u = (t >= off) ? ls[t - off] : 0;
    __syncthreads();
    ls[t] += u;
    __syncthreads();
  }
  if (g < NN) rowptr[g] = ls[t] - v;  // block-local exclusive
  if (t == SCANB - 1) bsum[blockIdx.x] = ls[t];
}

__global__ __launch_bounds__(128) void scan2(int* __restrict__ bsum,
                                             int* __restrict__ boff) {
  __shared__ int ls[128];
  int t = threadIdx.x;
  int v = (t < NB) ? bsum[t] : 0;
  ls[t] = v;
  __syncthreads();
#pragma unroll
  for (int off = 1; off < 128; off <<= 1) {
    int u = (t >= off) ? ls[t - off] : 0;
    __syncthreads();
    ls[t] += u;
    __syncthreads();
  }
  if (t < NB) boff[t] = ls[t] - v;
}

__global__ __launch_bounds__(SCANB) void scan3(int* __restrict__ rowptr,
                                               int* __restrict__ cursor,
                                               const int* __restrict__ boff) {
  int g = blockIdx.x * SCANB + threadIdx.x;
  if (g < NN) {
    int v = rowptr[g] + boff[blockIdx.x];
    rowptr[g] = v;
    cursor[g] = v;
  }
  if (g == 0) rowptr[NN] = NE;
}

__global__ __launch_bounds__(256) void csr_fill(const int* __restrict__ edges,
                                                int* __restrict__ cursor,
                                                int* __restrict__ srcs) {
  int e = blockIdx.x * blockDim.x + threadIdx.x;
  if (e < NE) {
    int pos = atomicAdd(&cursor[edges[NE + e]], 1);
    srcs[pos] = edges[e];
  }
}

// Fused per-(dst,head) attention gather: logits -> softmax -> weighted V sum.
__global__ __launch_bounds__(256) void agg_csr(
    const int* __restrict__ rowptr, const int* __restrict__ srcs,
    const u16* __restrict__ qT, const u16* __restrict__ kT,
    const u16* __restrict__ vT, float* __restrict__ agg) {
  int i = blockIdx.x * blockDim.x + threadIdx.x;
  if (i >= NN * NH) return;
  int dst = i >> 2, h = i & 3;
  float qv[HD];
  {
    const uint4* qp = (const uint4*)(qT + (size_t)dst * HID + h * HD);
#pragma unroll
    for (int j = 0; j < 4; ++j) up8(qp[j], qv + j * 8);
  }
  float acc[HD];
#pragma unroll
  for (int j = 0; j < HD; ++j) acc[j] = 0.f;
  float z = 0.f;
  int b = rowptr[dst], e2 = rowptr[dst + 1];
  for (int idx = b; idx < e2; ++idx) {
    int src = srcs[idx];
    const uint4* kp = (const uint4*)(kT + (size_t)src * HID + h * HD);
    const uint4* vp = (const uint4*)(vT + (size_t)src * HID + h * HD);
    uint4 ka[4], va[4];
#pragma unroll
    for (int j = 0; j < 4; ++j) ka[j] = kp[j];
#pragma unroll
    for (int j = 0; j < 4; ++j) va[j] = vp[j];
    float tf[8];
    float s = 0.f;
#pragma unroll
    for (int j = 0; j < 4; ++j) {
      up8(ka[j], tf);
#pragma unroll
      for (int q = 0; q < 8; ++q) s += qv[j * 8 + q] * tf[q];
    }
    s = fminf(s, 60.f);
    float ev = __expf(s);
    z += ev;
#pragma unroll
    for (int j = 0; j < 4; ++j) {
      up8(va[j], tf);
#pragma unroll
      for (int q = 0; q < 8; ++q) acc[j * 8 + q] += ev * tf[q];
    }
  }
  float inv = 1.f / (z + 1e-16f);
  float* ap = agg + (size_t)dst * HID + h * HD;
#pragma unroll
  for (int j = 0; j < 8; ++j) {
    *(float4*)(ap + j * 4) = make_float4(acc[j * 4] * inv, acc[j * 4 + 1] * inv,
                                         acc[j * 4 + 2] * inv, acc[j * 4 + 3] * inv);
  }
}

// Build combined weights: WkA = Wk[l,t] * a_rel[l,r=t] * p_rel*scale, WvM = Wv[l,t] * m_rel[l,r=t]
__global__ void combine_w(const float* __restrict__ Wk, const float* __restrict__ bk,
                          const float* __restrict__ Wv, const float* __restrict__ bv,
                          const float* __restrict__ a_rel, const float* __restrict__ m_rel,
                          const float* __restrict__ p_rel,
                          float* __restrict__ WkA, float* __restrict__ bkA,
                          float* __restrict__ WvM, float* __restrict__ bvM, int l) {
  int t = blockIdx.x;       // source type == relation id
  int which = blockIdx.y;   // 0 => k-side, 1 => v-side
  const float* W  = (which == 0 ? Wk : Wv) + (size_t)(l * 2 + t) * HID * HID;
  const float* b  = (which == 0 ? bk : bv) + (size_t)(l * 2 + t) * HID;
  const float* Ar = (which == 0 ? a_rel : m_rel) + (size_t)(l * 2 + t) * NH * HD * HD;
  float* Wd = (which == 0 ? WkA : WvM) + (size_t)t * HID * HID;
  float* bd = (which == 0 ? bkA : bvM) + (size_t)t * HID;
  const float scale = 0.17677669529663687f;  // 1/sqrt(32)
  for (int idx = threadIdx.x; idx < HID * HID; idx += blockDim.x) {
    int i = idx >> 7, col = idx & 127;
    int h = col >> 5, e = col & 31;
    const float* ap = Ar + h * HD * HD + e;
    const float* wp = W + i * HID + h * HD;
    float s = 0.f;
#pragma unroll
    for (int d = 0; d < HD; ++d) s += wp[d] * ap[d * HD];
    if (which == 0) s *= p_rel[(l * 2 + t) * NH + h] * scale;
    Wd[idx] = s;
  }
  if (threadIdx.x < HID) {
    int col = threadIdx.x, h = col >> 5, e = col & 31;
    const float* ap = Ar + h * HD * HD + e;
    const float* bp = b + h * HD;
    float s = 0.f;
#pragma unroll
    for (int d = 0; d < HD; ++d) s += bp[d] * ap[d * HD];
    if (which == 0) s *= p_rel[(l * 2 + t) * NH + h] * scale;
    bd[col] = s;
  }
}

// C[M x 128] = epilogue( act_in(A[M x 128]) @ W[128 x 128] + b ), up to 3 weight sets sharing A.
template <int NMAT, bool INGELU, bool OUTRELU, bool SKIP, bool OBF16>
__global__ __launch_bounds__(256) void gemm128(
    const float* __restrict__ A, int M,
    const float* __restrict__ W0, const float* __restrict__ B0,
    const float* __restrict__ W1, const float* __restrict__ B1,
    const float* __restrict__ W2, const float* __restrict__ B2,
    void* __restrict__ O0, void* __restrict__ O1, void* __restrict__ O2,
    const float* __restrict__ hprev, const float* __restrict__ skipP, int resflag) {
  __shared__ float sA[BM * PA];
  const int tid = threadIdx.x;
  const int tx = tid & 15, ty = tid >> 4;
  const int r0 = blockIdx.x * BM;
  {
    int kv = tid & 31;   // float4 index within row
    int rb = tid >> 5;   // 0..7
#pragma unroll
    for (int pss = 0; pss < 8; ++pss) {
      int r = pss * 8 + rb;
      int gr = r0 + r;
      float4 v = make_float4(0.f, 0.f, 0.f, 0.f);
      if (gr < M) v = *(const float4*)(A + (size_t)gr * HID + kv * 4);
      if (INGELU) { v.x = geluf(v.x); v.y = geluf(v.y); v.z = geluf(v.z); v.w = geluf(v.w); }
      float* d = sA + r * PA + kv * 4;
      d[0] = v.x; d[1] = v.y; d[2] = v.z; d[3] = v.w;
    }
  }
  __syncthreads();

  const float* Ws[3] = {W0, W1, W2};
  const float* Bs[3] = {B0, B1, B2};
  void* Os[3] = {O0, O1, O2};

  float beta = 0.f;
  if (SKIP) beta = 1.f / (1.f + expf(-skipP[0]));

#pragma unroll
  for (int mat = 0; mat < NMAT; ++mat) {
    const float* __restrict__ W = Ws[mat];
    float acc[4][8];
#pragma unroll
    for (int m = 0; m < 4; ++m)
#pragma unroll
      for (int j = 0; j < 8; ++j) acc[m][j] = 0.f;
    const float* Wp = W + tx * 8;
#pragma unroll 4
    for (int k = 0; k < HID; ++k) {
      float4 w0 = *(const float4*)(Wp + (size_t)k * HID);
      float4 w1 = *(const float4*)(Wp + (size_t)k * HID + 4);
#pragma unroll
      for (int m = 0; m < 4; ++m) {
        float a = sA[(ty + 16 * m) * PA + k];
        acc[m][0] += a * w0.x; acc[m][1] += a * w0.y;
        acc[m][2] += a * w0.z; acc[m][3] += a * w0.w;
        acc[m][4] += a * w1.x; acc[m][5] += a * w1.y;
        acc[m][6] += a * w1.z; acc[m][7] += a * w1.w;
      }
    }
    const float* Bp = Bs[mat] + tx * 8;
    float bias[8];
#pragma unroll
    for (int j = 0; j < 8; ++j) bias[j] = Bp[j];
#pragma unroll
    for (int m = 0; m < 4; ++m) {
      int r = r0 + ty + 16 * m;
      if (r >= M) continue;
      float o[8];
#pragma unroll
      for (int j = 0; j < 8; ++j) {
        float v = acc[m][j] + bias[j];
        if (OUTRELU) v = fmaxf(v, 0.f);
        o[j] = v;
      }
      if (SKIP) {
        const float* hp = hprev + (size_t)r * HID + tx * 8;
#pragma unroll
        for (int j = 0; j < 8; ++j) {
          float h = hp[j];
          float v = beta * o[j] + (1.f - beta) * h;
          if (resflag) v += h;
          o[j] = v;
        }
      }
      if (OBF16) {
        u16* Ob = (u16*)Os[mat] + (size_t)r * HID + tx * 8;
        union { u16 s[8]; uint4 v; } pk;
#pragma unroll
        for (int j = 0; j < 8; ++j) pk.s[j] = f2b(o[j]);
        *(uint4*)Ob = pk.v;
      } else {
        float* Of = (float*)Os[mat] + (size_t)r * HID + tx * 8;
        *(float4*)Of = make_float4(o[0], o[1], o[2], o[3]);
        *(float4*)(Of + 4) = make_float4(o[4], o[5], o[6], o[7]);
      }
    }
  }
}

extern "C" void kernel_launch(void* const* d_in, const int* in_sizes, int n_in,
                              void* d_out, int out_size, void* d_ws, size_t ws_size,
                              hipStream_t stream) {
  const float* x_user = (const float*)d_in[0];
  const float* x_item = (const float*)d_in[1];
  const float* W_in = (const float*)d_in[2];
  const float* b_in = (const float*)d_in[3];
  const float* Wk = (const float*)d_in[4];
  const float* bk = (const float*)d_in[5];
  const float* Wq = (const float*)d_in[6];
  const float* bq = (const float*)d_in[7];
  const float* Wv = (const float*)d_in[8];
  const float* bv = (const float*)d_in[9];
  const float* a_rel = (const float*)d_in[10];
  const float* m_rel = (const float*)d_in[11];
  const float* p_rel = (const float*)d_in[12];
  const float* Wo = (const float*)d_in[13];
  const float* bo = (const float*)d_in[14];
  const float* skipP = (const float*)d_in[15];
  const int* edge_ui = (const int*)d_in[16];
  const int* edge_iu = (const int*)d_in[17];
  float* out = (float*)d_out;

  char* p = (char*)d_ws;
  auto take = [&](size_t bytes) {
    void* r = (void*)p;
    p += (bytes + 255) & ~(size_t)255;
    return r;
  };
  size_t nodeF = (size_t)NN * HID * sizeof(float);
  size_t nodeB = (size_t)NN * HID * sizeof(u16);
  float* hA[2] = {(float*)take(nodeF), (float*)take(nodeF)};
  float* hB[2] = {(float*)take(nodeF), (float*)take(nodeF)};
  u16* qb[2] = {(u16*)take(nodeB), (u16*)take(nodeB)};
  u16* kb[2] = {(u16*)take(nodeB), (u16*)take(nodeB)};
  u16* vb[2] = {(u16*)take(nodeB), (u16*)take(nodeB)};
  int* deg    = (int*)take((size_t)NN * 4);
  int* cursor = (int*)take((size_t)NN * 4);
  int* bsum   = (int*)take((size_t)NB * 4);
  int* boff   = (int*)take((size_t)NB * 4);
  int* rowptr[2] = {(int*)take((size_t)(NN + 1) * 4), (int*)take((size_t)(NN + 1) * 4)};
  int* srcs[2]   = {(int*)take((size_t)NE * 4), (int*)take((size_t)NE * 4)};
  float* WkA = (float*)take((size_t)2 * HID * HID * 4);
  float* bkA = (float*)take((size_t)2 * HID * 4);
  float* WvM = (float*)take((size_t)2 * HID * HID * 4);
  float* bvM = (float*)take((size_t)2 * HID * 4);
  size_t used = (size_t)(p - (char*)d_ws);
  if (used > ws_size) {
    fprintf(stderr, "HGT kernel: workspace too small: need %zu, have %zu\n", used, ws_size);
    return;
  }

  const int GB = (NN + BM - 1) / BM;
  const int EB = (NE + 255) / 256;
  dim3 blk(256);
  const int* eidx[2] = {edge_ui, edge_iu};

  // ---- CSR build (once; shared by both layers) ----
  for (int r = 0; r < 2; ++r) {
    hipMemsetAsync(deg, 0, (size_t)NN * 4, stream);
    csr_count<<<EB, blk, 0, stream>>>(eidx[r], deg);
    scan1<<<NB, SCANB, 0, stream>>>(deg, rowptr[r], bsum);
    scan2<<<1, 128, 0, stream>>>(bsum, boff);
    scan3<<<NB, SCANB, 0, stream>>>(rowptr[r], cursor, boff);
    csr_fill<<<EB, blk, 0, stream>>>(eidx[r], cursor, srcs[r]);
  }

  // ---- input linear + relu ----
  gemm128<1, false, true, false, false><<<GB, blk, 0, stream>>>(
      x_user, NN, W_in, b_in, nullptr, nullptr, nullptr, nullptr,
      hA[0], nullptr, nullptr, nullptr, nullptr, 0);
  gemm128<1, false, true, false, false><<<GB, blk, 0, stream>>>(
      x_item, NN, W_in + HID * HID, b_in + HID, nullptr, nullptr, nullptr, nullptr,
      hA[1], nullptr, nullptr, nullptr, nullptr, 0);

  float* cur[2] = {hA[0], hA[1]};
  float* nxt[2] = {hB[0], hB[1]};
  const int AGB = (NN * NH + 255) / 256;

  for (int l = 0; l < LL; ++l) {
    combine_w<<<dim3(2, 2), blk, 0, stream>>>(Wk, bk, Wv, bv, a_rel, m_rel, p_rel,
                                              WkA, bkA, WvM, bvM, l);
    for (int t = 0; t < 2; ++t) {
      gemm128<3, false, false, false, true><<<GB, blk, 0, stream>>>(
          cur[t], NN,
          Wq + (size_t)(l * 2 + t) * HID * HID, bq + (size_t)(l * 2 + t) * HID,
          WkA + (size_t)t * HID * HID, bkA + (size_t)t * HID,
          WvM + (size_t)t * HID * HID, bvM + (size_t)t * HID,
          qb[t], kb[t], vb[t], nullptr, nullptr, 0);
    }
    for (int r = 0; r < 2; ++r) {
      int st = r, dt = 1 - r;
      agg_csr<<<AGB, blk, 0, stream>>>(rowptr[r], srcs[r], qb[dt], kb[st], vb[st], nxt[dt]);
    }
    for (int t = 0; t < 2; ++t) {
      float* outp = (l == LL - 1) ? (out + (size_t)t * NN * HID) : nxt[t];
      gemm128<1, true, false, true, false><<<GB, blk, 0, stream>>>(
          nxt[t], NN, Wo + (size_t)(l * 2 + t) * HID * HID, bo + (size_t)(l * 2 + t) * HID,
          nullptr, nullptr, nullptr, nullptr,
          outp, nullptr, nullptr, cur[t], skipP + (l * 2 + t), l > 0 ? 1 : 0);
    }
    if (l == 0) {
      float* t0 = cur[0]; float* t1 = cur[1];
      cur[0] = nxt[0]; cur[1] = nxt[1];
      nxt[0] = t0; nxt[1] = t1;
    }
  }
}

// Round 5
// 1227.853 us; speedup vs baseline: 12.5215x; 1.3165x over previous
//
#include <hip/hip_runtime.h>
#include <stdint.h>
#include <stdio.h>

#define NN 100000
#define NE 500000
#define HID 128
#define NH 4
#define HD 32
#define LL 2
#define SCANB 1024
#define NB ((NN + SCANB - 1) / SCANB)

typedef unsigned short u16;
typedef unsigned int u32;
typedef __attribute__((ext_vector_type(8))) short bfrag;   // 8 bf16 = 4 VGPR
typedef __attribute__((ext_vector_type(4))) float f32x4;

__device__ __forceinline__ float b2f(u32 lo16) {
  union { u32 u; float f; } c; c.u = lo16; return c.f;
}
__device__ __forceinline__ u16 f2b(float f) {
  union { float f; u32 u; } c; c.f = f;
  u32 u = c.u;
  u32 r = (u + 0x7FFFu + ((u >> 16) & 1u)) >> 16;
  return (u16)r;
}
__device__ __forceinline__ float geluf(float x) {
  return 0.5f * x * (1.0f + erff(x * 0.70710678118654752f));
}
__device__ __forceinline__ void up8(uint4 a, float* f) {
  f[0] = b2f(a.x << 16); f[1] = b2f(a.x & 0xFFFF0000u);
  f[2] = b2f(a.y << 16); f[3] = b2f(a.y & 0xFFFF0000u);
  f[4] = b2f(a.z << 16); f[5] = b2f(a.z & 0xFFFF0000u);
  f[6] = b2f(a.w << 16); f[7] = b2f(a.w & 0xFFFF0000u);
}

// ---------------- CSR build ----------------
__global__ __launch_bounds__(256) void csr_count(const int* __restrict__ edges,
                                                 int* __restrict__ deg) {
  int e = blockIdx.x * blockDim.x + threadIdx.x;
  if (e < NE) atomicAdd(&deg[edges[NE + e]], 1);
}

__global__ __launch_bounds__(SCANB) void scan1(const int* __restrict__ deg,
                                               int* __restrict__ rowptr,
                                               int* __restrict__ bsum) {
  __shared__ int ls[SCANB];
  int t = threadIdx.x;
  int g = blockIdx.x * SCANB + t;
  int v = (g < NN) ? deg[g] : 0;
  ls[t] = v;
  __syncthreads();
#pragma unroll
  for (int off = 1; off < SCANB; off <<= 1) {
    int u = (t >= off) ? ls[t - off] : 0;
    __syncthreads();
    ls[t] += u;
    __syncthreads();
  }
  if (g < NN) rowptr[g] = ls[t] - v;
  if (t == SCANB - 1) bsum[blockIdx.x] = ls[t];
}

__global__ __launch_bounds__(128) void scan2(int* __restrict__ bsum,
                                             int* __restrict__ boff) {
  __shared__ int ls[128];
  int t = threadIdx.x;
  int v = (t < NB) ? bsum[t] : 0;
  ls[t] = v;
  __syncthreads();
#pragma unroll
  for (int off = 1; off < 128; off <<= 1) {
    int u = (t >= off) ? ls[t - off] : 0;
    __syncthreads();
    ls[t] += u;
    __syncthreads();
  }
  if (t < NB) boff[t] = ls[t] - v;
}

__global__ __launch_bounds__(SCANB) void scan3(int* __restrict__ rowptr,
                                               int* __restrict__ cursor,
                                               const int* __restrict__ boff) {
  int g = blockIdx.x * SCANB + threadIdx.x;
  if (g < NN) {
    int v = rowptr[g] + boff[blockIdx.x];
    rowptr[g] = v;
    cursor[g] = v;
  }
  if (g == 0) rowptr[NN] = NE;
}

__global__ __launch_bounds__(256) void csr_fill(const int* __restrict__ edges,
                                                int* __restrict__ cursor,
                                                int* __restrict__ srcs) {
  int e = blockIdx.x * blockDim.x + threadIdx.x;
  if (e < NE) {
    int pos = atomicAdd(&cursor[edges[NE + e]], 1);
    srcs[pos] = edges[e];
  }
}

// ---------------- weight prep ----------------
// fp32 -> bf16 elementwise convert (8/thread)
__global__ __launch_bounds__(256) void cvt_f32_bf16(const float* __restrict__ s,
                                                    u16* __restrict__ d, int n) {
  int i = (blockIdx.x * 256 + threadIdx.x) * 8;
  if (i >= n) return;
  float4 a = *(const float4*)(s + i);
  float4 b = *(const float4*)(s + i + 4);
  union { u16 u[8]; uint4 v; } pk;
  pk.u[0] = f2b(a.x); pk.u[1] = f2b(a.y); pk.u[2] = f2b(a.z); pk.u[3] = f2b(a.w);
  pk.u[4] = f2b(b.x); pk.u[5] = f2b(b.y); pk.u[6] = f2b(b.z); pk.u[7] = f2b(b.w);
  *(uint4*)(d + i) = pk.v;
}

// transpose+cvt [128][128] fp32 -> bf16 [n][k]; optional bias copy
__global__ void prep_wT(const float* __restrict__ src, int srcStride,
                        u16* __restrict__ dst, int dstStride,
                        const float* __restrict__ bsrc, int bsStride,
                        float* __restrict__ bdst, int bdStride) {
  int m = blockIdx.x;
  const float* S = src + (size_t)m * srcStride;
  u16* D = dst + (size_t)m * dstStride;
  for (int i = threadIdx.x; i < HID * HID; i += 256) {
    int k = i >> 7, n = i & 127;
    D[n * HID + k] = f2b(S[i]);
  }
  if (bsrc != nullptr && threadIdx.x < HID)
    bdst[(size_t)m * bdStride + threadIdx.x] = bsrc[(size_t)m * bsStride + threadIdx.x];
}

// WkA^T = (Wk[l,t] · a_rel[l,t] · p·scale)^T bf16 -> wqkvT slot 1; WvM^T -> slot 2
__global__ void combine_w(const float* __restrict__ Wk, const float* __restrict__ bk,
                          const float* __restrict__ Wv, const float* __restrict__ bv,
                          const float* __restrict__ a_rel, const float* __restrict__ m_rel,
                          const float* __restrict__ p_rel,
                          u16* __restrict__ wqkvT, float* __restrict__ bqkv, int l) {
  int t = blockIdx.x;       // source type == relation id
  int which = blockIdx.y;   // 0 => k-side (slot 1), 1 => v-side (slot 2)
  const float* W  = (which == 0 ? Wk : Wv) + (size_t)(l * 2 + t) * HID * HID;
  const float* b  = (which == 0 ? bk : bv) + (size_t)(l * 2 + t) * HID;
  const float* Ar = (which == 0 ? a_rel : m_rel) + (size_t)(l * 2 + t) * NH * HD * HD;
  u16* Wd = wqkvT + ((size_t)t * 3 + 1 + which) * HID * HID;
  float* bd = bqkv + ((size_t)t * 3 + 1 + which) * HID;
  const float scale = 0.17677669529663687f;  // 1/sqrt(32)
  for (int idx = threadIdx.x; idx < HID * HID; idx += blockDim.x) {
    int i = idx >> 7, col = idx & 127;
    int h = col >> 5, e = col & 31;
    const float* ap = Ar + h * HD * HD + e;
    const float* wp = W + i * HID + h * HD;
    float s = 0.f;
#pragma unroll
    for (int d = 0; d < HD; ++d) s += wp[d] * ap[d * HD];
    if (which == 0) s *= p_rel[(l * 2 + t) * NH + h] * scale;
    Wd[(size_t)col * HID + i] = f2b(s);   // transposed store
  }
  if (threadIdx.x < HID) {
    int col = threadIdx.x, h = col >> 5, e = col & 31;
    const float* ap = Ar + h * HD * HD + e;
    const float* bp = b + h * HD;
    float s = 0.f;
#pragma unroll
    for (int d = 0; d < HD; ++d) s += bp[d] * ap[d * HD];
    if (which == 0) s *= p_rel[(l * 2 + t) * NH + h] * scale;
    bd[col] = s;
  }
}

// ---------------- MFMA GEMM ----------------
// C[M x 128] = epilogue( A[M x 128](bf16) @ W + b ), W given as WT[n][k] bf16,
// NMAT weight sets share A. Block: 4 waves x 32 rows = 128 rows.
// mfma(a=WT-frag, b=A-frag): D reg axis = out-col -> packed 8B bf16 stores.
template <int NMAT, bool RELU, bool SKIP>
__global__ __launch_bounds__(256) void mfgemm(
    const u16* __restrict__ A, int M,
    const u16* __restrict__ WT, const float* __restrict__ bias,
    u16* __restrict__ O0, u16* __restrict__ O1, u16* __restrict__ O2,
    float* __restrict__ Of,
    const float* __restrict__ hprev, const float* __restrict__ skipP, int resflag) {
  const int lane = threadIdx.x & 63;
  const int wid = threadIdx.x >> 6;
  const int l16 = lane & 15, g = lane >> 4;
  const int rbase = blockIdx.x * 128 + wid * 32;

  float beta = 0.f;
  if (SKIP) beta = 1.f / (1.f + __expf(-skipP[0]));

  // A fragments: rt in {0,1} row-tiles of 16, ks in {0..3} K-steps of 32.
  // lane l16 = row-in-tile, chunk (ks*4+g) = 16B of that row.
  bfrag af[2][4];
  int rowA[2];
#pragma unroll
  for (int rt = 0; rt < 2; ++rt) {
    int row = rbase + rt * 16 + l16;
    rowA[rt] = row;
    int rl = row < M ? row : M - 1;
    const bfrag* ap = (const bfrag*)(A + (size_t)rl * HID);
#pragma unroll
    for (int ks = 0; ks < 4; ++ks) af[rt][ks] = ap[ks * 4 + g];
  }

  u16* Os[3] = {O0, O1, O2};
#pragma unroll
  for (int m = 0; m < NMAT; ++m) {
    f32x4 acc[2][8];
#pragma unroll
    for (int rt = 0; rt < 2; ++rt)
#pragma unroll
      for (int ct = 0; ct < 8; ++ct) acc[rt][ct] = (f32x4){0.f, 0.f, 0.f, 0.f};
#pragma unroll
    for (int ct = 0; ct < 8; ++ct) {
      const bfrag* wp = (const bfrag*)(WT + ((size_t)m * HID + ct * 16 + l16) * HID);
      bfrag wf[4];
#pragma unroll
      for (int ks = 0; ks < 4; ++ks) wf[ks] = wp[ks * 4 + g];
#pragma unroll
      for (int ks = 0; ks < 4; ++ks)
#pragma unroll
        for (int rt = 0; rt < 2; ++rt)
          acc[rt][ct] = __builtin_amdgcn_mfma_f32_16x16x32_bf16(wf[ks], af[rt][ks],
                                                                acc[rt][ct], 0, 0, 0);
    }
    u16* Ob = Os[m];
#pragma unroll
    for (int rt = 0; rt < 2; ++rt) {
      int row = rowA[rt];
      if (row >= M) continue;
#pragma unroll
      for (int ct = 0; ct < 8; ++ct) {
        int nc = ct * 16 + g * 4;
        const float4 bb = *(const float4*)(bias + m * HID + nc);
        float o0 = acc[rt][ct][0] + bb.x;
        float o1 = acc[rt][ct][1] + bb.y;
        float o2 = acc[rt][ct][2] + bb.z;
        float o3 = acc[rt][ct][3] + bb.w;
        if (RELU) {
          o0 = fmaxf(o0, 0.f); o1 = fmaxf(o1, 0.f);
          o2 = fmaxf(o2, 0.f); o3 = fmaxf(o3, 0.f);
        }
        if (SKIP) {
          const float4 hh = *(const float4*)(hprev + (size_t)row * HID + nc);
          o0 = beta * o0 + (1.f - beta) * hh.x;
          o1 = beta * o1 + (1.f - beta) * hh.y;
          o2 = beta * o2 + (1.f - beta) * hh.z;
          o3 = beta * o3 + (1.f - beta) * hh.w;
          if (resflag) { o0 += hh.x; o1 += hh.y; o2 += hh.z; o3 += hh.w; }
        }
        u32 lo = (u32)f2b(o0) | ((u32)f2b(o1) << 16);
        u32 hi = (u32)f2b(o2) | ((u32)f2b(o3) << 16);
        *(uint2*)(Ob + (size_t)row * HID + nc) = make_uint2(lo, hi);
        if (NMAT == 1 && Of != nullptr) {
          *(float4*)(Of + (size_t)row * HID + nc) = make_float4(o0, o1, o2, o3);
        }
      }
    }
  }
}

// Fused per-(dst,head) attention gather: logits -> softmax -> weighted V -> gelu -> bf16
__global__ __launch_bounds__(256) void agg_csr(
    const int* __restrict__ rowptr, const int* __restrict__ srcs,
    const u16* __restrict__ qT, const u16* __restrict__ kT,
    const u16* __restrict__ vT, u16* __restrict__ aggb) {
  int i = blockIdx.x * blockDim.x + threadIdx.x;
  if (i >= NN * NH) return;
  int dst = i >> 2, h = i & 3;
  float qv[HD];
  {
    const uint4* qp = (const uint4*)(qT + (size_t)dst * HID + h * HD);
#pragma unroll
    for (int j = 0; j < 4; ++j) up8(qp[j], qv + j * 8);
  }
  float acc[HD];
#pragma unroll
  for (int j = 0; j < HD; ++j) acc[j] = 0.f;
  float z = 0.f;
  int b = rowptr[dst], e2 = rowptr[dst + 1];
  for (int idx = b; idx < e2; ++idx) {
    int src = srcs[idx];
    const uint4* kp = (const uint4*)(kT + (size_t)src * HID + h * HD);
    const uint4* vp = (const uint4*)(vT + (size_t)src * HID + h * HD);
    uint4 ka[4], va[4];
#pragma unroll
    for (int j = 0; j < 4; ++j) ka[j] = kp[j];
#pragma unroll
    for (int j = 0; j < 4; ++j) va[j] = vp[j];
    float tf[8];
    float s = 0.f;
#pragma unroll
    for (int j = 0; j < 4; ++j) {
      up8(ka[j], tf);
#pragma unroll
      for (int q = 0; q < 8; ++q) s += qv[j * 8 + q] * tf[q];
    }
    s = fminf(s, 60.f);
    float ev = __expf(s);
    z += ev;
#pragma unroll
    for (int j = 0; j < 4; ++j) {
      up8(va[j], tf);
#pragma unroll
      for (int q = 0; q < 8; ++q) acc[j * 8 + q] += ev * tf[q];
    }
  }
  float inv = 1.f / (z + 1e-16f);
  u16* ap = aggb + (size_t)dst * HID + h * HD;
  u32 w[16];
#pragma unroll
  for (int j = 0; j < 16; ++j) {
    float a0 = geluf(acc[2 * j] * inv);
    float a1 = geluf(acc[2 * j + 1] * inv);
    w[j] = (u32)f2b(a0) | ((u32)f2b(a1) << 16);
  }
#pragma unroll
  for (int j = 0; j < 4; ++j)
    *(uint4*)(ap + j * 8) = make_uint4(w[4 * j], w[4 * j + 1], w[4 * j + 2], w[4 * j + 3]);
}

extern "C" void kernel_launch(void* const* d_in, const int* in_sizes, int n_in,
                              void* d_out, int out_size, void* d_ws, size_t ws_size,
                              hipStream_t stream) {
  const float* x_user = (const float*)d_in[0];
  const float* x_item = (const float*)d_in[1];
  const float* W_in = (const float*)d_in[2];
  const float* b_in = (const float*)d_in[3];
  const float* Wk = (const float*)d_in[4];
  const float* bk = (const float*)d_in[5];
  const float* Wq = (const float*)d_in[6];
  const float* bq = (const float*)d_in[7];
  const float* Wv = (const float*)d_in[8];
  const float* bv = (const float*)d_in[9];
  const float* a_rel = (const float*)d_in[10];
  const float* m_rel = (const float*)d_in[11];
  const float* p_rel = (const float*)d_in[12];
  const float* Wo = (const float*)d_in[13];
  const float* bo = (const float*)d_in[14];
  const float* skipP = (const float*)d_in[15];
  const int* edge_ui = (const int*)d_in[16];
  const int* edge_iu = (const int*)d_in[17];
  float* out = (float*)d_out;

  char* p = (char*)d_ws;
  auto take = [&](size_t bytes) {
    void* r = (void*)p;
    p += (bytes + 255) & ~(size_t)255;
    return r;
  };
  size_t nodeF = (size_t)NN * HID * sizeof(float);
  size_t nodeB = (size_t)NN * HID * sizeof(u16);
  float* hA[2] = {(float*)take(nodeF), (float*)take(nodeF)};   // fp32 h (in-place h0->h1)
  u16* nb0[2] = {(u16*)take(nodeB), (u16*)take(nodeB)};        // xb -> hb -> qb
  u16* kb[2] = {(u16*)take(nodeB), (u16*)take(nodeB)};
  u16* vb[2] = {(u16*)take(nodeB), (u16*)take(nodeB)};
  u16* aggb[2] = {(u16*)take(nodeB), (u16*)take(nodeB)};       // gelu'd agg / bf16 h(l+1)
  int* deg    = (int*)take((size_t)NN * 4);
  int* cursor = (int*)take((size_t)NN * 4);
  int* bsum   = (int*)take((size_t)NB * 4);
  int* boff   = (int*)take((size_t)NB * 4);
  int* rowptr[2] = {(int*)take((size_t)(NN + 1) * 4), (int*)take((size_t)(NN + 1) * 4)};
  int* srcs[2]   = {(int*)take((size_t)NE * 4), (int*)take((size_t)NE * 4)};
  u16* winT  = (u16*)take((size_t)2 * HID * HID * 2);
  u16* woT   = (u16*)take((size_t)4 * HID * HID * 2);
  u16* wqkvT = (u16*)take((size_t)2 * 3 * HID * HID * 2);      // per-layer [t][q,k,v]
  float* bqkv = (float*)take((size_t)2 * 3 * HID * 4);
  size_t used = (size_t)(p - (char*)d_ws);
  if (used > ws_size) {
    fprintf(stderr, "HGT kernel: workspace too small: need %zu, have %zu\n", used, ws_size);
    return;
  }

  const int GB = (NN + 127) / 128;
  const int EB = (NE + 255) / 256;
  dim3 blk(256);
  const int* eidx[2] = {edge_ui, edge_iu};

  // ---- CSR build (once; shared by both layers) ----
  for (int r = 0; r < 2; ++r) {
    hipMemsetAsync(deg, 0, (size_t)NN * 4, stream);
    csr_count<<<EB, blk, 0, stream>>>(eidx[r], deg);
    scan1<<<NB, SCANB, 0, stream>>>(deg, rowptr[r], bsum);
    scan2<<<1, 128, 0, stream>>>(bsum, boff);
    scan3<<<NB, SCANB, 0, stream>>>(rowptr[r], cursor, boff);
    csr_fill<<<EB, blk, 0, stream>>>(eidx[r], cursor, srcs[r]);
  }

  // ---- weight prep ----
  prep_wT<<<2, blk, 0, stream>>>(W_in, HID * HID, winT, HID * HID, nullptr, 0, nullptr, 0);
  prep_wT<<<4, blk, 0, stream>>>(Wo, HID * HID, woT, HID * HID, nullptr, 0, nullptr, 0);

  // ---- x -> bf16 ----
  const int CVB = (NN * HID / 8 + 255) / 256;
  cvt_f32_bf16<<<CVB, blk, 0, stream>>>(x_user, nb0[0], NN * HID);
  cvt_f32_bf16<<<CVB, blk, 0, stream>>>(x_item, nb0[1], NN * HID);

  // ---- input linear + relu (in-place bf16 A -> bf16 h, plus fp32 h) ----
  for (int t = 0; t < 2; ++t) {
    mfgemm<1, true, false><<<GB, blk, 0, stream>>>(
        nb0[t], NN, winT + (size_t)t * HID * HID, b_in + t * HID,
        nb0[t], nullptr, nullptr, hA[t], nullptr, nullptr, 0);
  }

  const int AGB = (NN * NH + 255) / 256;
  for (int l = 0; l < LL; ++l) {
    prep_wT<<<2, blk, 0, stream>>>(Wq + (size_t)l * 2 * HID * HID, HID * HID,
                                   wqkvT, 3 * HID * HID,
                                   bq + (size_t)l * 2 * HID, HID, bqkv, 3 * HID);
    combine_w<<<dim3(2, 2), blk, 0, stream>>>(Wk, bk, Wv, bv, a_rel, m_rel, p_rel,
                                              wqkvT, bqkv, l);
    const u16* hb[2] = {l == 0 ? nb0[0] : aggb[0], l == 0 ? nb0[1] : aggb[1]};
    // q/k/v projections (q written in place over bf16 h)
    for (int t = 0; t < 2; ++t) {
      mfgemm<3, false, false><<<GB, blk, 0, stream>>>(
          hb[t], NN, wqkvT + (size_t)t * 3 * HID * HID, bqkv + t * 3 * HID,
          nb0[t], kb[t], vb[t], nullptr, nullptr, nullptr, 0);
    }
    // attention gather (q = nb0)
    for (int r = 0; r < 2; ++r) {
      int st = r, dt = 1 - r;
      agg_csr<<<AGB, blk, 0, stream>>>(rowptr[r], srcs[r], nb0[dt], kb[st], vb[st], aggb[dt]);
    }
    // output linear + skip (A = gelu'd agg bf16; bf16 copy written in place;
    // fp32 h updated in place in hA, final layer writes d_out)
    for (int t = 0; t < 2; ++t) {
      float* outp = (l == LL - 1) ? (out + (size_t)t * NN * HID) : hA[t];
      mfgemm<1, false, true><<<GB, blk, 0, stream>>>(
          aggb[t], NN, woT + (size_t)(l * 2 + t) * HID * HID, bo + (size_t)(l * 2 + t) * HID,
          aggb[t], nullptr, nullptr, outp, hA[t], skipP + (l * 2 + t), l > 0 ? 1 : 0);
    }
  }
}

// Round 6
// 891.336 us; speedup vs baseline: 17.2489x; 1.3775x over previous
//
#include <hip/hip_runtime.h>
#include <stdint.h>
#include <stdio.h>

#define NN 100000
#define NE 500000
#define HID 128
#define NH 4
#define HD 32
#define LL 2
#define SCANB 1024
#define NB ((NN + SCANB - 1) / SCANB)

typedef unsigned short u16;
typedef unsigned int u32;
typedef __attribute__((ext_vector_type(8))) short bfrag;   // 8 bf16 = 4 VGPR
typedef __attribute__((ext_vector_type(4))) float f32x4;

__device__ __forceinline__ float b2f(u32 lo16) {
  union { u32 u; float f; } c; c.u = lo16; return c.f;
}
__device__ __forceinline__ u16 f2b(float f) {
  union { float f; u32 u; } c; c.f = f;
  u32 u = c.u;
  u32 r = (u + 0x7FFFu + ((u >> 16) & 1u)) >> 16;
  return (u16)r;
}
__device__ __forceinline__ float geluf(float x) {
  return 0.5f * x * (1.0f + erff(x * 0.70710678118654752f));
}
__device__ __forceinline__ void up8(uint4 a, float* f) {
  f[0] = b2f(a.x << 16); f[1] = b2f(a.x & 0xFFFF0000u);
  f[2] = b2f(a.y << 16); f[3] = b2f(a.y & 0xFFFF0000u);
  f[4] = b2f(a.z << 16); f[5] = b2f(a.z & 0xFFFF0000u);
  f[6] = b2f(a.w << 16); f[7] = b2f(a.w & 0xFFFF0000u);
}

// ---------------- CSR build ----------------
__global__ __launch_bounds__(256) void csr_count(const int* __restrict__ edges,
                                                 int* __restrict__ deg) {
  int e = blockIdx.x * blockDim.x + threadIdx.x;
  if (e < NE) atomicAdd(&deg[edges[NE + e]], 1);
}

__global__ __launch_bounds__(SCANB) void scan1(const int* __restrict__ deg,
                                               int* __restrict__ rowptr,
                                               int* __restrict__ bsum) {
  __shared__ int ls[SCANB];
  int t = threadIdx.x;
  int g = blockIdx.x * SCANB + t;
  int v = (g < NN) ? deg[g] : 0;
  ls[t] = v;
  __syncthreads();
#pragma unroll
  for (int off = 1; off < SCANB; off <<= 1) {
    int u = (t >= off) ? ls[t - off] : 0;
    __syncthreads();
    ls[t] += u;
    __syncthreads();
  }
  if (g < NN) rowptr[g] = ls[t] - v;
  if (t == SCANB - 1) bsum[blockIdx.x] = ls[t];
}

__global__ __launch_bounds__(128) void scan2(int* __restrict__ bsum,
                                             int* __restrict__ boff) {
  __shared__ int ls[128];
  int t = threadIdx.x;
  int v = (t < NB) ? bsum[t] : 0;
  ls[t] = v;
  __syncthreads();
#pragma unroll
  for (int off = 1; off < 128; off <<= 1) {
    int u = (t >= off) ? ls[t - off] : 0;
    __syncthreads();
    ls[t] += u;
    __syncthreads();
  }
  if (t < NB) boff[t] = ls[t] - v;
}

__global__ __launch_bounds__(SCANB) void scan3(int* __restrict__ rowptr,
                                               int* __restrict__ cursor,
                                               const int* __restrict__ boff) {
  int g = blockIdx.x * SCANB + threadIdx.x;
  if (g < NN) {
    int v = rowptr[g] + boff[blockIdx.x];
    rowptr[g] = v;
    cursor[g] = v;
  }
  if (g == 0) rowptr[NN] = NE;
}

__global__ __launch_bounds__(256) void csr_fill(const int* __restrict__ edges,
                                                int* __restrict__ cursor,
                                                int* __restrict__ srcs) {
  int e = blockIdx.x * blockDim.x + threadIdx.x;
  if (e < NE) {
    int pos = atomicAdd(&cursor[edges[NE + e]], 1);
    srcs[pos] = edges[e];
  }
}

// ---------------- weight prep (all upfront, wide grids) ----------------
__global__ __launch_bounds__(256) void cvt_f32_bf16(const float* __restrict__ s,
                                                    u16* __restrict__ d, int n) {
  int i = (blockIdx.x * 256 + threadIdx.x) * 8;
  if (i >= n) return;
  float4 a = *(const float4*)(s + i);
  float4 b = *(const float4*)(s + i + 4);
  union { u16 u[8]; uint4 v; } pk;
  pk.u[0] = f2b(a.x); pk.u[1] = f2b(a.y); pk.u[2] = f2b(a.z); pk.u[3] = f2b(a.w);
  pk.u[4] = f2b(b.x); pk.u[5] = f2b(b.y); pk.u[6] = f2b(b.z); pk.u[7] = f2b(b.w);
  *(uint4*)(d + i) = pk.v;
}

// transpose+cvt [128][128] fp32 -> bf16 [n][k]; grid (64 chunks, nmat)
__global__ __launch_bounds__(256) void prep_wT(const float* __restrict__ src, size_t srcStride,
                                               u16* __restrict__ dst, size_t dstStride,
                                               const float* __restrict__ bsrc, int bsStride,
                                               float* __restrict__ bdst, int bdStride) {
  int m = blockIdx.y;
  const float* S = src + (size_t)m * srcStride;
  u16* D = dst + (size_t)m * dstStride;
  int idx = blockIdx.x * 256 + threadIdx.x;
  int k = idx >> 7, n = idx & 127;
  D[(size_t)n * HID + k] = f2b(S[idx]);
  if (bsrc != nullptr && blockIdx.x == 0 && threadIdx.x < HID)
    bdst[(size_t)m * bdStride + threadIdx.x] = bsrc[(size_t)m * bsStride + threadIdx.x];
}

// (Wk·a_rel·p·scale)^T and (Wv·m_rel)^T for all l,t in one launch.
// grid (64 chunks, 4 = t*2+which, 2 = l)
__global__ __launch_bounds__(256) void combine_all(
    const float* __restrict__ Wk, const float* __restrict__ bk,
    const float* __restrict__ Wv, const float* __restrict__ bv,
    const float* __restrict__ a_rel, const float* __restrict__ m_rel,
    const float* __restrict__ p_rel,
    u16* __restrict__ wqkvT, float* __restrict__ bqkv) {
  int l = blockIdx.z;
  int t = blockIdx.y >> 1, which = blockIdx.y & 1;
  const float* W  = (which == 0 ? Wk : Wv) + (size_t)(l * 2 + t) * HID * HID;
  const float* b  = (which == 0 ? bk : bv) + (size_t)(l * 2 + t) * HID;
  const float* Ar = (which == 0 ? a_rel : m_rel) + (size_t)(l * 2 + t) * NH * HD * HD;
  u16* Wd = wqkvT + ((size_t)(l * 2 + t) * 3 + 1 + which) * HID * HID;
  float* bd = bqkv + ((size_t)(l * 2 + t) * 3 + 1 + which) * HID;
  const float scale = 0.17677669529663687f;  // 1/sqrt(32)
  int idx = blockIdx.x * 256 + threadIdx.x;
  int i = idx >> 7, col = idx & 127;
  int h = col >> 5, e = col & 31;
  {
    const float* ap = Ar + h * HD * HD + e;
    const float* wp = W + (size_t)i * HID + h * HD;
    float s = 0.f;
#pragma unroll
    for (int d = 0; d < HD; ++d) s += wp[d] * ap[d * HD];
    if (which == 0) s *= p_rel[(l * 2 + t) * NH + h] * scale;
    Wd[(size_t)col * HID + i] = f2b(s);
  }
  if (blockIdx.x == 0 && threadIdx.x < HID) {
    int col = threadIdx.x, h2 = col >> 5, e2 = col & 31;
    const float* ap = Ar + h2 * HD * HD + e2;
    const float* bp = b + h2 * HD;
    float s = 0.f;
#pragma unroll
    for (int d = 0; d < HD; ++d) s += bp[d] * ap[d * HD];
    if (which == 0) s *= p_rel[(l * 2 + t) * NH + h2] * scale;
    bd[col] = s;
  }
}

// ---------------- MFMA GEMM (both node types in one launch) ----------------
// t = blockIdx.x >= gb. C[M x 128] = epilogue( A_t @ W_t + b_t ).
template <int NMAT, bool RELU, bool SKIP>
__global__ __launch_bounds__(256) void mfgemm(
    const u16* __restrict__ A0, const u16* __restrict__ A1, int M, int gb,
    const u16* __restrict__ WT, size_t wtStride,
    const float* __restrict__ bias, size_t biasStride,
    u16* __restrict__ O00, u16* __restrict__ O01, u16* __restrict__ O02,
    u16* __restrict__ O10, u16* __restrict__ O11, u16* __restrict__ O12,
    float* __restrict__ Of0, float* __restrict__ Of1,
    const float* __restrict__ hp0, const float* __restrict__ hp1,
    const float* __restrict__ skipP, int resflag) {
  const int t = blockIdx.x >= gb;
  const int bx = t ? blockIdx.x - gb : blockIdx.x;
  const u16* A = t ? A1 : A0;
  const u16* W = WT + (size_t)t * wtStride;
  const float* bs = bias + (size_t)t * biasStride;
  u16* Os[3];
  Os[0] = t ? O10 : O00; Os[1] = t ? O11 : O01; Os[2] = t ? O12 : O02;
  float* Of = t ? Of1 : Of0;
  const float* hprev = t ? hp1 : hp0;

  const int lane = threadIdx.x & 63;
  const int wid = threadIdx.x >> 6;
  const int l16 = lane & 15, g = lane >> 4;
  const int rbase = bx * 128 + wid * 32;

  float beta = 0.f;
  if (SKIP) beta = 1.f / (1.f + __expf(-skipP[t]));

  bfrag af[2][4];
  int rowA[2];
#pragma unroll
  for (int rt = 0; rt < 2; ++rt) {
    int row = rbase + rt * 16 + l16;
    rowA[rt] = row;
    int rl = row < M ? row : M - 1;
    const bfrag* ap = (const bfrag*)(A + (size_t)rl * HID);
#pragma unroll
    for (int ks = 0; ks < 4; ++ks) af[rt][ks] = ap[ks * 4 + g];
  }

#pragma unroll
  for (int m = 0; m < NMAT; ++m) {
    f32x4 acc[2][8];
#pragma unroll
    for (int rt = 0; rt < 2; ++rt)
#pragma unroll
      for (int ct = 0; ct < 8; ++ct) acc[rt][ct] = (f32x4){0.f, 0.f, 0.f, 0.f};
#pragma unroll
    for (int ct = 0; ct < 8; ++ct) {
      const bfrag* wp = (const bfrag*)(W + ((size_t)m * HID + ct * 16 + l16) * HID);
      bfrag wf[4];
#pragma unroll
      for (int ks = 0; ks < 4; ++ks) wf[ks] = wp[ks * 4 + g];
#pragma unroll
      for (int ks = 0; ks < 4; ++ks)
#pragma unroll
        for (int rt = 0; rt < 2; ++rt)
          acc[rt][ct] = __builtin_amdgcn_mfma_f32_16x16x32_bf16(wf[ks], af[rt][ks],
                                                                acc[rt][ct], 0, 0, 0);
    }
    u16* Ob = Os[m];
#pragma unroll
    for (int rt = 0; rt < 2; ++rt) {
      int row = rowA[rt];
      if (row >= M) continue;
#pragma unroll
      for (int ct = 0; ct < 8; ++ct) {
        int nc = ct * 16 + g * 4;
        const float4 bb = *(const float4*)(bs + m * HID + nc);
        float o0 = acc[rt][ct][0] + bb.x;
        float o1 = acc[rt][ct][1] + bb.y;
        float o2 = acc[rt][ct][2] + bb.z;
        float o3 = acc[rt][ct][3] + bb.w;
        if (RELU) {
          o0 = fmaxf(o0, 0.f); o1 = fmaxf(o1, 0.f);
          o2 = fmaxf(o2, 0.f); o3 = fmaxf(o3, 0.f);
        }
        if (SKIP) {
          const float4 hh = *(const float4*)(hprev + (size_t)row * HID + nc);
          o0 = beta * o0 + (1.f - beta) * hh.x;
          o1 = beta * o1 + (1.f - beta) * hh.y;
          o2 = beta * o2 + (1.f - beta) * hh.z;
          o3 = beta * o3 + (1.f - beta) * hh.w;
          if (resflag) { o0 += hh.x; o1 += hh.y; o2 += hh.z; o3 += hh.w; }
        }
        u32 lo = (u32)f2b(o0) | ((u32)f2b(o1) << 16);
        u32 hi = (u32)f2b(o2) | ((u32)f2b(o3) << 16);
        *(uint2*)(Ob + (size_t)row * HID + nc) = make_uint2(lo, hi);
        if (NMAT == 1 && Of != nullptr) {
          *(float4*)(Of + (size_t)row * HID + nc) = make_float4(o0, o1, o2, o3);
        }
      }
    }
  }
}

// Fused per-(dst,head) attention gather, both relations in one launch.
__global__ __launch_bounds__(256) void agg_csr(
    const int* __restrict__ rp0, const int* __restrict__ ss0,
    const u16* __restrict__ q0, const u16* __restrict__ k0,
    const u16* __restrict__ v0, u16* __restrict__ o0,
    const int* __restrict__ rp1, const int* __restrict__ ss1,
    const u16* __restrict__ q1, const u16* __restrict__ k1,
    const u16* __restrict__ v1, u16* __restrict__ o1, int agb) {
  const int r = blockIdx.x >= agb;
  const int bx = r ? blockIdx.x - agb : blockIdx.x;
  int i = bx * 256 + threadIdx.x;
  if (i >= NN * NH) return;
  const int* rowptr = r ? rp1 : rp0;
  const int* srcs = r ? ss1 : ss0;
  const u16* qT = r ? q1 : q0;
  const u16* kT = r ? k1 : k0;
  const u16* vT = r ? v1 : v0;
  u16* aggb = r ? o1 : o0;

  int dst = i >> 2, h = i & 3;
  float qv[HD];
  {
    const uint4* qp = (const uint4*)(qT + (size_t)dst * HID + h * HD);
#pragma unroll
    for (int j = 0; j < 4; ++j) up8(qp[j], qv + j * 8);
  }
  float acc[HD];
#pragma unroll
  for (int j = 0; j < HD; ++j) acc[j] = 0.f;
  float z = 0.f;
  int b = rowptr[dst], e2 = rowptr[dst + 1];
  for (int idx = b; idx < e2; ++idx) {
    int src = srcs[idx];
    const uint4* kp = (const uint4*)(kT + (size_t)src * HID + h * HD);
    const uint4* vp = (const uint4*)(vT + (size_t)src * HID + h * HD);
    uint4 ka[4], va[4];
#pragma unroll
    for (int j = 0; j < 4; ++j) ka[j] = kp[j];
#pragma unroll
    for (int j = 0; j < 4; ++j) va[j] = vp[j];
    float tf[8];
    float s = 0.f;
#pragma unroll
    for (int j = 0; j < 4; ++j) {
      up8(ka[j], tf);
#pragma unroll
      for (int q = 0; q < 8; ++q) s += qv[j * 8 + q] * tf[q];
    }
    s = fminf(s, 60.f);
    float ev = __expf(s);
    z += ev;
#pragma unroll
    for (int j = 0; j < 4; ++j) {
      up8(va[j], tf);
#pragma unroll
      for (int q = 0; q < 8; ++q) acc[j * 8 + q] += ev * tf[q];
    }
  }
  float inv = 1.f / (z + 1e-16f);
  u16* ap = aggb + (size_t)dst * HID + h * HD;
  u32 w[16];
#pragma unroll
  for (int j = 0; j < 16; ++j) {
    float a0 = geluf(acc[2 * j] * inv);
    float a1 = geluf(acc[2 * j + 1] * inv);
    w[j] = (u32)f2b(a0) | ((u32)f2b(a1) << 16);
  }
#pragma unroll
  for (int j = 0; j < 4; ++j)
    *(uint4*)(ap + j * 8) = make_uint4(w[4 * j], w[4 * j + 1], w[4 * j + 2], w[4 * j + 3]);
}

extern "C" void kernel_launch(void* const* d_in, const int* in_sizes, int n_in,
                              void* d_out, int out_size, void* d_ws, size_t ws_size,
                              hipStream_t stream) {
  const float* x_user = (const float*)d_in[0];
  const float* x_item = (const float*)d_in[1];
  const float* W_in = (const float*)d_in[2];
  const float* b_in = (const float*)d_in[3];
  const float* Wk = (const float*)d_in[4];
  const float* bk = (const float*)d_in[5];
  const float* Wq = (const float*)d_in[6];
  const float* bq = (const float*)d_in[7];
  const float* Wv = (const float*)d_in[8];
  const float* bv = (const float*)d_in[9];
  const float* a_rel = (const float*)d_in[10];
  const float* m_rel = (const float*)d_in[11];
  const float* p_rel = (const float*)d_in[12];
  const float* Wo = (const float*)d_in[13];
  const float* bo = (const float*)d_in[14];
  const float* skipP = (const float*)d_in[15];
  const int* edge_ui = (const int*)d_in[16];
  const int* edge_iu = (const int*)d_in[17];
  float* out = (float*)d_out;

  char* p = (char*)d_ws;
  auto take = [&](size_t bytes) {
    void* r = (void*)p;
    p += (bytes + 255) & ~(size_t)255;
    return r;
  };
  size_t nodeF = (size_t)NN * HID * sizeof(float);
  size_t nodeB = (size_t)NN * HID * sizeof(u16);
  float* hA[2] = {(float*)take(nodeF), (float*)take(nodeF)};   // fp32 h (in-place h0->h1)
  u16* nb0[2] = {(u16*)take(nodeB), (u16*)take(nodeB)};        // xb -> hb -> qb
  u16* kb[2] = {(u16*)take(nodeB), (u16*)take(nodeB)};
  u16* vb[2] = {(u16*)take(nodeB), (u16*)take(nodeB)};
  u16* aggb[2] = {(u16*)take(nodeB), (u16*)take(nodeB)};       // gelu'd agg / bf16 h(l+1)
  int* deg    = (int*)take((size_t)NN * 4);
  int* cursor = (int*)take((size_t)NN * 4);
  int* bsum   = (int*)take((size_t)NB * 4);
  int* boff   = (int*)take((size_t)NB * 4);
  int* rowptr[2] = {(int*)take((size_t)(NN + 1) * 4), (int*)take((size_t)(NN + 1) * 4)};
  int* srcs[2]   = {(int*)take((size_t)NE * 4), (int*)take((size_t)NE * 4)};
  u16* winT  = (u16*)take((size_t)2 * HID * HID * 2);
  u16* woT   = (u16*)take((size_t)4 * HID * HID * 2);
  u16* wqkvT = (u16*)take((size_t)2 * 2 * 3 * HID * HID * 2);  // [l][t][q,k,v]
  float* bqkv = (float*)take((size_t)2 * 2 * 3 * HID * 4);
  size_t used = (size_t)(p - (char*)d_ws);
  if (used > ws_size) {
    fprintf(stderr, "HGT kernel: workspace too small: need %zu, have %zu\n", used, ws_size);
    return;
  }

  const int GB = (NN + 127) / 128;
  const int EB = (NE + 255) / 256;
  dim3 blk(256);
  const int* eidx[2] = {edge_ui, edge_iu};

  // ---- CSR build (once; shared by both layers) ----
  for (int r = 0; r < 2; ++r) {
    hipMemsetAsync(deg, 0, (size_t)NN * 4, stream);
    csr_count<<<EB, blk, 0, stream>>>(eidx[r], deg);
    scan1<<<NB, SCANB, 0, stream>>>(deg, rowptr[r], bsum);
    scan2<<<1, 128, 0, stream>>>(bsum, boff);
    scan3<<<NB, SCANB, 0, stream>>>(rowptr[r], cursor, boff);
    csr_fill<<<EB, blk, 0, stream>>>(eidx[r], cursor, srcs[r]);
  }

  // ---- weight prep (all upfront, wide grids) ----
  prep_wT<<<dim3(64, 2), blk, 0, stream>>>(W_in, HID * HID, winT, HID * HID,
                                           nullptr, 0, nullptr, 0);
  prep_wT<<<dim3(64, 4), blk, 0, stream>>>(Wo, HID * HID, woT, HID * HID,
                                           nullptr, 0, nullptr, 0);
  prep_wT<<<dim3(64, 4), blk, 0, stream>>>(Wq, HID * HID, wqkvT, 3 * HID * HID,
                                           bq, HID, bqkv, 3 * HID);
  combine_all<<<dim3(64, 4, 2), blk, 0, stream>>>(Wk, bk, Wv, bv, a_rel, m_rel, p_rel,
                                                  wqkvT, bqkv);

  // ---- x -> bf16 ----
  const int CVB = (NN * HID / 8 + 255) / 256;
  cvt_f32_bf16<<<CVB, blk, 0, stream>>>(x_user, nb0[0], NN * HID);
  cvt_f32_bf16<<<CVB, blk, 0, stream>>>(x_item, nb0[1], NN * HID);

  // ---- input linear + relu (both types, one launch) ----
  mfgemm<1, true, false><<<2 * GB, blk, 0, stream>>>(
      nb0[0], nb0[1], NN, GB, winT, HID * HID, b_in, HID,
      nb0[0], nullptr, nullptr, nb0[1], nullptr, nullptr,
      hA[0], hA[1], nullptr, nullptr, nullptr, 0);

  const int AGB = (NN * NH + 255) / 256;
  for (int l = 0; l < LL; ++l) {
    const u16* hb[2] = {l == 0 ? nb0[0] : aggb[0], l == 0 ? nb0[1] : aggb[1]};
    // q/k/v projections, both types (q written in place over bf16 h)
    mfgemm<3, false, false><<<2 * GB, blk, 0, stream>>>(
        hb[0], hb[1], NN, GB,
        wqkvT + (size_t)l * 2 * 3 * HID * HID, 3 * HID * HID,
        bqkv + (size_t)l * 2 * 3 * HID, 3 * HID,
        nb0[0], kb[0], vb[0], nb0[1], kb[1], vb[1],
        nullptr, nullptr, nullptr, nullptr, nullptr, 0);
    // attention gather, both relations (r: st=r, dt=1-r)
    agg_csr<<<2 * AGB, blk, 0, stream>>>(
        rowptr[0], srcs[0], nb0[1], kb[0], vb[0], aggb[1],
        rowptr[1], srcs[1], nb0[0], kb[1], vb[1], aggb[0], AGB);
    // output linear + skip, both types (bf16 copy in place; fp32 h in place in hA)
    float* of0 = (l == LL - 1) ? out : hA[0];
    float* of1 = (l == LL - 1) ? (out + (size_t)NN * HID) : hA[1];
    mfgemm<1, false, true><<<2 * GB, blk, 0, stream>>>(
        aggb[0], aggb[1], NN, GB,
        woT + (size_t)l * 2 * HID * HID, HID * HID,
        bo + (size_t)l * 2 * HID, HID,
        aggb[0], nullptr, nullptr, aggb[1], nullptr, nullptr,
        of0, of1, hA[0], hA[1], skipP + l * 2, l > 0 ? 1 : 0);
  }
}

// Round 7
// 717.837 us; speedup vs baseline: 21.4179x; 1.2417x over previous
//
#include <hip/hip_runtime.h>
#include <stdint.h>
#include <stdio.h>

#define NN 100000
#define NE 500000
#define HID 128
#define NH 4
#define HD 32
#define LL 2
#define SCANB 1024
#define NB ((NN + SCANB - 1) / SCANB)

typedef unsigned short u16;
typedef unsigned int u32;
typedef __attribute__((ext_vector_type(8))) short bfrag;   // 8 bf16 = 4 VGPR
typedef __attribute__((ext_vector_type(4))) float f32x4;

__device__ __forceinline__ float b2f(u32 lo16) {
  union { u32 u; float f; } c; c.u = lo16; return c.f;
}
__device__ __forceinline__ u16 f2b(float f) {
  union { float f; u32 u; } c; c.f = f;
  u32 u = c.u;
  u32 r = (u + 0x7FFFu + ((u >> 16) & 1u)) >> 16;
  return (u16)r;
}
__device__ __forceinline__ float geluf(float x) {
  return 0.5f * x * (1.0f + erff(x * 0.70710678118654752f));
}
__device__ __forceinline__ void up8(uint4 a, float* f) {
  f[0] = b2f(a.x << 16); f[1] = b2f(a.x & 0xFFFF0000u);
  f[2] = b2f(a.y << 16); f[3] = b2f(a.y & 0xFFFF0000u);
  f[4] = b2f(a.z << 16); f[5] = b2f(a.z & 0xFFFF0000u);
  f[6] = b2f(a.w << 16); f[7] = b2f(a.w & 0xFFFF0000u);
}

// ---------------- CSR build ----------------
__global__ __launch_bounds__(256) void csr_count(const int* __restrict__ edges,
                                                 int* __restrict__ deg) {
  int e = blockIdx.x * blockDim.x + threadIdx.x;
  if (e < NE) atomicAdd(&deg[edges[NE + e]], 1);
}

__global__ __launch_bounds__(SCANB) void scan1(const int* __restrict__ deg,
                                               int* __restrict__ rowptr,
                                               int* __restrict__ bsum) {
  __shared__ int ls[SCANB];
  int t = threadIdx.x;
  int g = blockIdx.x * SCANB + t;
  int v = (g < NN) ? deg[g] : 0;
  ls[t] = v;
  __syncthreads();
#pragma unroll
  for (int off = 1; off < SCANB; off <<= 1) {
    int u = (t >= off) ? ls[t - off] : 0;
    __syncthreads();
    ls[t] += u;
    __syncthreads();
  }
  if (g < NN) rowptr[g] = ls[t] - v;
  if (t == SCANB - 1) bsum[blockIdx.x] = ls[t];
}

__global__ __launch_bounds__(128) void scan2(int* __restrict__ bsum,
                                             int* __restrict__ boff) {
  __shared__ int ls[128];
  int t = threadIdx.x;
  int v = (t < NB) ? bsum[t] : 0;
  ls[t] = v;
  __syncthreads();
#pragma unroll
  for (int off = 1; off < 128; off <<= 1) {
    int u = (t >= off) ? ls[t - off] : 0;
    __syncthreads();
    ls[t] += u;
    __syncthreads();
  }
  if (t < NB) boff[t] = ls[t] - v;
}

__global__ __launch_bounds__(SCANB) void scan3(int* __restrict__ rowptr,
                                               int* __restrict__ cursor,
                                               const int* __restrict__ boff) {
  int g = blockIdx.x * SCANB + threadIdx.x;
  if (g < NN) {
    int v = rowptr[g] + boff[blockIdx.x];
    rowptr[g] = v;
    cursor[g] = v;
  }
  if (g == 0) rowptr[NN] = NE;
}

__global__ __launch_bounds__(256) void csr_fill(const int* __restrict__ edges,
                                                int* __restrict__ cursor,
                                                int* __restrict__ srcs) {
  int e = blockIdx.x * blockDim.x + threadIdx.x;
  if (e < NE) {
    int pos = atomicAdd(&cursor[edges[NE + e]], 1);
    srcs[pos] = edges[e];
  }
}

// ---------------- weight prep (all upfront, wide grids) ----------------
__global__ __launch_bounds__(256) void cvt_f32_bf16(const float* __restrict__ s,
                                                    u16* __restrict__ d, int n) {
  int i = (blockIdx.x * 256 + threadIdx.x) * 8;
  if (i >= n) return;
  float4 a = *(const float4*)(s + i);
  float4 b = *(const float4*)(s + i + 4);
  union { u16 u[8]; uint4 v; } pk;
  pk.u[0] = f2b(a.x); pk.u[1] = f2b(a.y); pk.u[2] = f2b(a.z); pk.u[3] = f2b(a.w);
  pk.u[4] = f2b(b.x); pk.u[5] = f2b(b.y); pk.u[6] = f2b(b.z); pk.u[7] = f2b(b.w);
  *(uint4*)(d + i) = pk.v;
}

// transpose+cvt [128][128] fp32 -> bf16 [n][k]; grid (64 chunks, nmat)
__global__ __launch_bounds__(256) void prep_wT(const float* __restrict__ src, size_t srcStride,
                                               u16* __restrict__ dst, size_t dstStride,
                                               const float* __restrict__ bsrc, int bsStride,
                                               float* __restrict__ bdst, int bdStride) {
  int m = blockIdx.y;
  const float* S = src + (size_t)m * srcStride;
  u16* D = dst + (size_t)m * dstStride;
  int idx = blockIdx.x * 256 + threadIdx.x;
  int k = idx >> 7, n = idx & 127;
  D[(size_t)n * HID + k] = f2b(S[idx]);
  if (bsrc != nullptr && blockIdx.x == 0 && threadIdx.x < HID)
    bdst[(size_t)m * bdStride + threadIdx.x] = bsrc[(size_t)m * bsStride + threadIdx.x];
}

// (Wk·a_rel·p·scale)^T and (Wv·m_rel)^T for all l,t in one launch.
// grid (64 chunks, 4 = t*2+which, 2 = l)
__global__ __launch_bounds__(256) void combine_all(
    const float* __restrict__ Wk, const float* __restrict__ bk,
    const float* __restrict__ Wv, const float* __restrict__ bv,
    const float* __restrict__ a_rel, const float* __restrict__ m_rel,
    const float* __restrict__ p_rel,
    u16* __restrict__ wqkvT, float* __restrict__ bqkv) {
  int l = blockIdx.z;
  int t = blockIdx.y >> 1, which = blockIdx.y & 1;
  const float* W  = (which == 0 ? Wk : Wv) + (size_t)(l * 2 + t) * HID * HID;
  const float* b  = (which == 0 ? bk : bv) + (size_t)(l * 2 + t) * HID;
  const float* Ar = (which == 0 ? a_rel : m_rel) + (size_t)(l * 2 + t) * NH * HD * HD;
  u16* Wd = wqkvT + ((size_t)(l * 2 + t) * 3 + 1 + which) * HID * HID;
  float* bd = bqkv + ((size_t)(l * 2 + t) * 3 + 1 + which) * HID;
  const float scale = 0.17677669529663687f;  // 1/sqrt(32)
  int idx = blockIdx.x * 256 + threadIdx.x;
  int i = idx >> 7, col = idx & 127;
  int h = col >> 5, e = col & 31;
  {
    const float* ap = Ar + h * HD * HD + e;
    const float* wp = W + (size_t)i * HID + h * HD;
    float s = 0.f;
#pragma unroll
    for (int d = 0; d < HD; ++d) s += wp[d] * ap[d * HD];
    if (which == 0) s *= p_rel[(l * 2 + t) * NH + h] * scale;
    Wd[(size_t)col * HID + i] = f2b(s);
  }
  if (blockIdx.x == 0 && threadIdx.x < HID) {
    int col = threadIdx.x, h2 = col >> 5, e2 = col & 31;
    const float* ap = Ar + h2 * HD * HD + e2;
    const float* bp = b + h2 * HD;
    float s = 0.f;
#pragma unroll
    for (int d = 0; d < HD; ++d) s += bp[d] * ap[d * HD];
    if (which == 0) s *= p_rel[(l * 2 + t) * NH + h2] * scale;
    bd[col] = s;
  }
}

// ---------------- MFMA GEMM (both node types in one launch) ----------------
// t = blockIdx.x >= gb. C[M x 128] = epilogue( A_t @ W_t + b_t ).
// W staged per-mat into LDS (32KB) via global_load_lds with XOR-swizzled
// global source + swizzled ds_read (T2/m201 both-sides pattern).
template <int NMAT, bool RELU, bool SKIP>
__global__ __launch_bounds__(256) void mfgemm(
    const u16* __restrict__ A0, const u16* __restrict__ A1, int M, int gb,
    const u16* __restrict__ WT, size_t wtStride,
    const float* __restrict__ bias, size_t biasStride,
    u16* __restrict__ O00, u16* __restrict__ O01, u16* __restrict__ O02,
    u16* __restrict__ O10, u16* __restrict__ O11, u16* __restrict__ O12,
    float* __restrict__ Of0, float* __restrict__ Of1,
    const float* __restrict__ hp0, const float* __restrict__ hp1,
    const float* __restrict__ skipP, int resflag) {
  __shared__ __align__(16) u16 sW[HID * HID];   // 32 KB, one mat at a time
  const int t = blockIdx.x >= gb;
  const int bx = t ? blockIdx.x - gb : blockIdx.x;
  const u16* A = t ? A1 : A0;
  const u16* Wg = WT + (size_t)t * wtStride;
  const float* bs = bias + (size_t)t * biasStride;
  u16* Os[3];
  Os[0] = t ? O10 : O00; Os[1] = t ? O11 : O01; Os[2] = t ? O12 : O02;
  float* Of = t ? Of1 : Of0;
  const float* hprev = t ? hp1 : hp0;

  const int lane = threadIdx.x & 63;
  const int wid = threadIdx.x >> 6;
  const int l16 = lane & 15, g = lane >> 4;
  const int rbase = bx * 128 + wid * 32;

  float beta = 0.f;
  if (SKIP) beta = 1.f / (1.f + __expf(-skipP[t]));

  // Stage W[mat] into LDS: linear dest, inverse-swizzled global source.
  // 16B-chunk o16 = instr*64 + lane; dest row = o16>>4, chunk = o16&15;
  // src chunk = chunk ^ (row&7)  (involution within each 256B row).
  auto stageW = [&](int m) {
    const u16* Wm = Wg + (size_t)m * HID * HID;
#pragma unroll
    for (int j = 0; j < 8; ++j) {
      int ins = wid * 8 + j;
      int o16 = ins * 64 + lane;
      int row = o16 >> 4, ch = o16 & 15;
      const u16* src = Wm + (size_t)row * HID + ((ch ^ (row & 7)) << 3);
      u16* dst = sW + (size_t)ins * 512;   // wave-uniform 1KB chunk base
      __builtin_amdgcn_global_load_lds(
          (const __attribute__((address_space(1))) unsigned int*)src,
          (__attribute__((address_space(3))) unsigned int*)dst, 16, 0, 0);
    }
  };

  // A fragments direct from global (issued before staging; drained by barrier)
  bfrag af[2][4];
  int rowA[2];
#pragma unroll
  for (int rt = 0; rt < 2; ++rt) {
    int row = rbase + rt * 16 + l16;
    rowA[rt] = row;
    int rl = row < M ? row : M - 1;
    const bfrag* ap = (const bfrag*)(A + (size_t)rl * HID);
#pragma unroll
    for (int ks = 0; ks < 4; ++ks) af[rt][ks] = ap[ks * 4 + g];
  }

  stageW(0);
  __syncthreads();

#pragma unroll
  for (int m = 0; m < NMAT; ++m) {
    f32x4 acc[2][8];
#pragma unroll
    for (int rt = 0; rt < 2; ++rt)
#pragma unroll
      for (int ct = 0; ct < 8; ++ct) acc[rt][ct] = (f32x4){0.f, 0.f, 0.f, 0.f};
#pragma unroll
    for (int ct = 0; ct < 8; ++ct) {
      int row = ct * 16 + l16;
      bfrag wf[4];
#pragma unroll
      for (int ks = 0; ks < 4; ++ks)
        wf[ks] = *(const bfrag*)&sW[(size_t)row * HID + (((ks * 4 + g) ^ (row & 7)) << 3)];
#pragma unroll
      for (int ks = 0; ks < 4; ++ks)
#pragma unroll
        for (int rt = 0; rt < 2; ++rt)
          acc[rt][ct] = __builtin_amdgcn_mfma_f32_16x16x32_bf16(wf[ks], af[rt][ks],
                                                                acc[rt][ct], 0, 0, 0);
    }
    if (m + 1 < NMAT) {
      __syncthreads();        // all waves done reading sW
      stageW(m + 1);          // async; overlaps epilogue below
    }
    u16* Ob = Os[m];
#pragma unroll
    for (int rt = 0; rt < 2; ++rt) {
      int row = rowA[rt];
      if (row >= M) continue;
#pragma unroll
      for (int ct = 0; ct < 8; ++ct) {
        int nc = ct * 16 + g * 4;
        const float4 bb = *(const float4*)(bs + m * HID + nc);
        float o0 = acc[rt][ct][0] + bb.x;
        float o1 = acc[rt][ct][1] + bb.y;
        float o2 = acc[rt][ct][2] + bb.z;
        float o3 = acc[rt][ct][3] + bb.w;
        if (RELU) {
          o0 = fmaxf(o0, 0.f); o1 = fmaxf(o1, 0.f);
          o2 = fmaxf(o2, 0.f); o3 = fmaxf(o3, 0.f);
        }
        if (SKIP) {
          const float4 hh = *(const float4*)(hprev + (size_t)row * HID + nc);
          o0 = beta * o0 + (1.f - beta) * hh.x;
          o1 = beta * o1 + (1.f - beta) * hh.y;
          o2 = beta * o2 + (1.f - beta) * hh.z;
          o3 = beta * o3 + (1.f - beta) * hh.w;
          if (resflag) { o0 += hh.x; o1 += hh.y; o2 += hh.z; o3 += hh.w; }
        }
        u32 lo = (u32)f2b(o0) | ((u32)f2b(o1) << 16);
        u32 hi = (u32)f2b(o2) | ((u32)f2b(o3) << 16);
        *(uint2*)(Ob + (size_t)row * HID + nc) = make_uint2(lo, hi);
        if (NMAT == 1 && Of != nullptr) {
          *(float4*)(Of + (size_t)row * HID + nc) = make_float4(o0, o1, o2, o3);
        }
      }
    }
    if (m + 1 < NMAT) __syncthreads();   // staging of next mat complete
  }
}

// Fused per-(dst,head) attention gather, both relations in one launch.
__global__ __launch_bounds__(256) void agg_csr(
    const int* __restrict__ rp0, const int* __restrict__ ss0,
    const u16* __restrict__ q0, const u16* __restrict__ k0,
    const u16* __restrict__ v0, u16* __restrict__ o0,
    const int* __restrict__ rp1, const int* __restrict__ ss1,
    const u16* __restrict__ q1, const u16* __restrict__ k1,
    const u16* __restrict__ v1, u16* __restrict__ o1, int agb) {
  const int r = blockIdx.x >= agb;
  const int bx = r ? blockIdx.x - agb : blockIdx.x;
  int i = bx * 256 + threadIdx.x;
  if (i >= NN * NH) return;
  const int* rowptr = r ? rp1 : rp0;
  const int* srcs = r ? ss1 : ss0;
  const u16* qT = r ? q1 : q0;
  const u16* kT = r ? k1 : k0;
  const u16* vT = r ? v1 : v0;
  u16* aggb = r ? o1 : o0;

  int dst = i >> 2, h = i & 3;
  float qv[HD];
  {
    const uint4* qp = (const uint4*)(qT + (size_t)dst * HID + h * HD);
#pragma unroll
    for (int j = 0; j < 4; ++j) up8(qp[j], qv + j * 8);
  }
  float acc[HD];
#pragma unroll
  for (int j = 0; j < HD; ++j) acc[j] = 0.f;
  float z = 0.f;
  int b = rowptr[dst], e2 = rowptr[dst + 1];
  for (int idx = b; idx < e2; ++idx) {
    int src = srcs[idx];
    const uint4* kp = (const uint4*)(kT + (size_t)src * HID + h * HD);
    const uint4* vp = (const uint4*)(vT + (size_t)src * HID + h * HD);
    uint4 ka[4], va[4];
#pragma unroll
    for (int j = 0; j < 4; ++j) ka[j] = kp[j];
#pragma unroll
    for (int j = 0; j < 4; ++j) va[j] = vp[j];
    float tf[8];
    float s = 0.f;
#pragma unroll
    for (int j = 0; j < 4; ++j) {
      up8(ka[j], tf);
#pragma unroll
      for (int q = 0; q < 8; ++q) s += qv[j * 8 + q] * tf[q];
    }
    s = fminf(s, 60.f);
    float ev = __expf(s);
    z += ev;
#pragma unroll
    for (int j = 0; j < 4; ++j) {
      up8(va[j], tf);
#pragma unroll
      for (int q = 0; q < 8; ++q) acc[j * 8 + q] += ev * tf[q];
    }
  }
  float inv = 1.f / (z + 1e-16f);
  u16* ap = aggb + (size_t)dst * HID + h * HD;
  u32 w[16];
#pragma unroll
  for (int j = 0; j < 16; ++j) {
    float a0 = geluf(acc[2 * j] * inv);
    float a1 = geluf(acc[2 * j + 1] * inv);
    w[j] = (u32)f2b(a0) | ((u32)f2b(a1) << 16);
  }
#pragma unroll
  for (int j = 0; j < 4; ++j)
    *(uint4*)(ap + j * 8) = make_uint4(w[4 * j], w[4 * j + 1], w[4 * j + 2], w[4 * j + 3]);
}

extern "C" void kernel_launch(void* const* d_in, const int* in_sizes, int n_in,
                              void* d_out, int out_size, void* d_ws, size_t ws_size,
                              hipStream_t stream) {
  const float* x_user = (const float*)d_in[0];
  const float* x_item = (const float*)d_in[1];
  const float* W_in = (const float*)d_in[2];
  const float* b_in = (const float*)d_in[3];
  const float* Wk = (const float*)d_in[4];
  const float* bk = (const float*)d_in[5];
  const float* Wq = (const float*)d_in[6];
  const float* bq = (const float*)d_in[7];
  const float* Wv = (const float*)d_in[8];
  const float* bv = (const float*)d_in[9];
  const float* a_rel = (const float*)d_in[10];
  const float* m_rel = (const float*)d_in[11];
  const float* p_rel = (const float*)d_in[12];
  const float* Wo = (const float*)d_in[13];
  const float* bo = (const float*)d_in[14];
  const float* skipP = (const float*)d_in[15];
  const int* edge_ui = (const int*)d_in[16];
  const int* edge_iu = (const int*)d_in[17];
  float* out = (float*)d_out;

  char* p = (char*)d_ws;
  auto take = [&](size_t bytes) {
    void* r = (void*)p;
    p += (bytes + 255) & ~(size_t)255;
    return r;
  };
  size_t nodeF = (size_t)NN * HID * sizeof(float);
  size_t nodeB = (size_t)NN * HID * sizeof(u16);
  float* hA[2] = {(float*)take(nodeF), (float*)take(nodeF)};   // fp32 h (in-place h0->h1)
  u16* nb0[2] = {(u16*)take(nodeB), (u16*)take(nodeB)};        // xb -> hb -> qb
  u16* kb[2] = {(u16*)take(nodeB), (u16*)take(nodeB)};
  u16* vb[2] = {(u16*)take(nodeB), (u16*)take(nodeB)};
  u16* aggb[2] = {(u16*)take(nodeB), (u16*)take(nodeB)};       // gelu'd agg / bf16 h(l+1)
  int* deg    = (int*)take((size_t)NN * 4);
  int* cursor = (int*)take((size_t)NN * 4);
  int* bsum   = (int*)take((size_t)NB * 4);
  int* boff   = (int*)take((size_t)NB * 4);
  int* rowptr[2] = {(int*)take((size_t)(NN + 1) * 4), (int*)take((size_t)(NN + 1) * 4)};
  int* srcs[2]   = {(int*)take((size_t)NE * 4), (int*)take((size_t)NE * 4)};
  u16* winT  = (u16*)take((size_t)2 * HID * HID * 2);
  u16* woT   = (u16*)take((size_t)4 * HID * HID * 2);
  u16* wqkvT = (u16*)take((size_t)2 * 2 * 3 * HID * HID * 2);  // [l][t][q,k,v]
  float* bqkv = (float*)take((size_t)2 * 2 * 3 * HID * 4);
  size_t used = (size_t)(p - (char*)d_ws);
  if (used > ws_size) {
    fprintf(stderr, "HGT kernel: workspace too small: need %zu, have %zu\n", used, ws_size);
    return;
  }

  const int GB = (NN + 127) / 128;
  const int EB = (NE + 255) / 256;
  dim3 blk(256);
  const int* eidx[2] = {edge_ui, edge_iu};

  // ---- CSR build (once; shared by both layers) ----
  for (int r = 0; r < 2; ++r) {
    hipMemsetAsync(deg, 0, (size_t)NN * 4, stream);
    csr_count<<<EB, blk, 0, stream>>>(eidx[r], deg);
    scan1<<<NB, SCANB, 0, stream>>>(deg, rowptr[r], bsum);
    scan2<<<1, 128, 0, stream>>>(bsum, boff);
    scan3<<<NB, SCANB, 0, stream>>>(rowptr[r], cursor, boff);
    csr_fill<<<EB, blk, 0, stream>>>(eidx[r], cursor, srcs[r]);
  }

  // ---- weight prep (all upfront, wide grids) ----
  prep_wT<<<dim3(64, 2), blk, 0, stream>>>(W_in, HID * HID, winT, HID * HID,
                                           nullptr, 0, nullptr, 0);
  prep_wT<<<dim3(64, 4), blk, 0, stream>>>(Wo, HID * HID, woT, HID * HID,
                                           nullptr, 0, nullptr, 0);
  prep_wT<<<dim3(64, 4), blk, 0, stream>>>(Wq, HID * HID, wqkvT, 3 * HID * HID,
                                           bq, HID, bqkv, 3 * HID);
  combine_all<<<dim3(64, 4, 2), blk, 0, stream>>>(Wk, bk, Wv, bv, a_rel, m_rel, p_rel,
                                                  wqkvT, bqkv);

  // ---- x -> bf16 ----
  const int CVB = (NN * HID / 8 + 255) / 256;
  cvt_f32_bf16<<<CVB, blk, 0, stream>>>(x_user, nb0[0], NN * HID);
  cvt_f32_bf16<<<CVB, blk, 0, stream>>>(x_item, nb0[1], NN * HID);

  // ---- input linear + relu (both types, one launch) ----
  mfgemm<1, true, false><<<2 * GB, blk, 0, stream>>>(
      nb0[0], nb0[1], NN, GB, winT, HID * HID, b_in, HID,
      nb0[0], nullptr, nullptr, nb0[1], nullptr, nullptr,
      hA[0], hA[1], nullptr, nullptr, nullptr, 0);

  const int AGB = (NN * NH + 255) / 256;
  for (int l = 0; l < LL; ++l) {
    const u16* hb[2] = {l == 0 ? nb0[0] : aggb[0], l == 0 ? nb0[1] : aggb[1]};
    // q/k/v projections, both types (q written in place over bf16 h)
    mfgemm<3, false, false><<<2 * GB, blk, 0, stream>>>(
        hb[0], hb[1], NN, GB,
        wqkvT + (size_t)l * 2 * 3 * HID * HID, 3 * HID * HID,
        bqkv + (size_t)l * 2 * 3 * HID, 3 * HID,
        nb0[0], kb[0], vb[0], nb0[1], kb[1], vb[1],
        nullptr, nullptr, nullptr, nullptr, nullptr, 0);
    // attention gather, both relations (r: st=r, dt=1-r)
    agg_csr<<<2 * AGB, blk, 0, stream>>>(
        rowptr[0], srcs[0], nb0[1], kb[0], vb[0], aggb[1],
        rowptr[1], srcs[1], nb0[0], kb[1], vb[1], aggb[0], AGB);
    // output linear + skip, both types (bf16 copy in place; fp32 h in place in hA)
    float* of0 = (l == LL - 1) ? out : hA[0];
    float* of1 = (l == LL - 1) ? (out + (size_t)NN * HID) : hA[1];
    mfgemm<1, false, true><<<2 * GB, blk, 0, stream>>>(
        aggb[0], aggb[1], NN, GB,
        woT + (size_t)l * 2 * HID * HID, HID * HID,
        bo + (size_t)l * 2 * HID, HID,
        aggb[0], nullptr, nullptr, aggb[1], nullptr, nullptr,
        of0, of1, hA[0], hA[1], skipP + l * 2, l > 0 ? 1 : 0);
  }
}